// Round 1
// baseline (9996.420 us; speedup 1.0000x reference)
//
#include <hip/hip_runtime.h>
#include <hip/hip_bf16.h>

#define N_NODES 50000
#define N_GRAPHS 64
#define HID 100

// workspace layout (float offsets)
#define OFF_DINV 0
#define OFF_CNT  50048
#define OFF_POOL 50112
#define OFF_HS   50176
#define OFF_ACC  (OFF_HS + N_NODES * HID)
#define OFF_H1   (OFF_ACC + N_NODES * HID)

__global__ void k_init(float* __restrict__ deg, float* __restrict__ pool,
                       float* __restrict__ cnt) {
    int i = blockIdx.x * blockDim.x + threadIdx.x;
    if (i < N_NODES) deg[i] = 1.0f;               // self-loop
    if (i < N_GRAPHS) { pool[i] = 0.0f; cnt[i] = 0.0f; }
}

__global__ void k_deg(const int* __restrict__ dst, float* __restrict__ deg, int E) {
    int e = blockIdx.x * blockDim.x + threadIdx.x;
    if (e < E) atomicAdd(&deg[dst[e]], 1.0f);
}

__global__ void k_dinv(float* __restrict__ d) {
    int i = blockIdx.x * blockDim.x + threadIdx.x;
    if (i < N_NODES) d[i] = rsqrtf(d[i]);         // deg >= 1 always
}

// hs[i][j] = dinv[i] * sum_k X[i][k] * W[k][j]; also written to acc (self-loop init).
// Block: 64 rows x 128 cols (cols 100..127 padded zero). 256 threads, 4x8 per thread.
template<int K>
__global__ __launch_bounds__(256) void k_gemm(const float* __restrict__ X,
                                              const float* __restrict__ W,
                                              const float* __restrict__ dinv,
                                              float* __restrict__ hs,
                                              float* __restrict__ accb) {
    __shared__ __align__(16) float xs[32][64];    // [k_local][row]
    __shared__ __align__(16) float ws[32][128];   // [k_local][col]
    const int t = threadIdx.x;
    const int base = blockIdx.x * 64;
    const int r0 = (t >> 4) * 4;     // 0..60
    const int c0 = (t & 15) * 8;     // 0..120
    const int f  = t & 7;            // x-stage float4 slot
    const int rr = t >> 3;           // x-stage row 0..31 / w-stage k 0..31
    const int cg = t & 7;            // w-stage col group

    float acc[4][8];
#pragma unroll
    for (int i = 0; i < 4; ++i)
#pragma unroll
        for (int j = 0; j < 8; ++j) acc[i][j] = 0.0f;

    for (int k0 = 0; k0 < K; k0 += 32) {
        // stage X^T tile
#pragma unroll
        for (int p = 0; p < 2; ++p) {
            int r = p * 32 + rr;
            int row = base + r;
#pragma unroll
            for (int u = 0; u < 4; ++u) {
                int k = k0 + 4 * f + u;
                float v = 0.0f;
                if (row < N_NODES && k < K) v = X[row * K + k];
                xs[4 * f + u][r] = v;
            }
        }
        // stage W tile (pad cols >= HID and k >= K with 0)
#pragma unroll
        for (int u = 0; u < 16; ++u) {
            int c = 16 * cg + u;
            int k = k0 + rr;
            float v = 0.0f;
            if (k < K && c < HID) v = W[k * HID + c];
            ws[rr][c] = v;
        }
        __syncthreads();

        for (int kk = 0; kk < 32; ++kk) {
            const float4 a  = *(const float4*)&xs[kk][r0];
            const float4 w0 = *(const float4*)&ws[kk][c0];
            const float4 w1 = *(const float4*)&ws[kk][c0 + 4];
            const float ar[4] = {a.x, a.y, a.z, a.w};
            const float wc[8] = {w0.x, w0.y, w0.z, w0.w, w1.x, w1.y, w1.z, w1.w};
#pragma unroll
            for (int i = 0; i < 4; ++i)
#pragma unroll
                for (int j = 0; j < 8; ++j) acc[i][j] += ar[i] * wc[j];
        }
        __syncthreads();
    }

    // epilogue: scale by dinv, write hs and acc (only cols < HID)
#pragma unroll
    for (int i = 0; i < 4; ++i) {
        int row = base + r0 + i;
        if (row >= N_NODES) continue;
        float di = dinv[row];
        float4 v0 = make_float4(di * acc[i][0], di * acc[i][1], di * acc[i][2], di * acc[i][3]);
        float4 v1 = make_float4(di * acc[i][4], di * acc[i][5], di * acc[i][6], di * acc[i][7]);
        float* hp = hs   + row * HID + c0;
        float* ap = accb + row * HID + c0;
        if (c0 < 96) {
            *(float4*)hp = v0; *(float4*)(hp + 4) = v1;
            *(float4*)ap = v0; *(float4*)(ap + 4) = v1;
        } else if (c0 == 96) {
            *(float4*)hp = v0;
            *(float4*)ap = v0;
        }
    }
}

// acc[dst] += hs[src], 25 float4 chunks per edge
__global__ void k_scatter(const int* __restrict__ src, const int* __restrict__ dst,
                          const float* __restrict__ hs, float* __restrict__ acc, int E) {
    int w = blockIdx.x * blockDim.x + threadIdx.x;
    if (w >= E * 25) return;
    int e = w / 25, jc = w % 25;
    int s = src[e], d = dst[e];
    float4 v = *(const float4*)&hs[s * HID + jc * 4];
    float* a = &acc[d * HID + jc * 4];
    atomicAdd(a + 0, v.x);
    atomicAdd(a + 1, v.y);
    atomicAdd(a + 2, v.z);
    atomicAdd(a + 3, v.w);
}

// h1 = tanh(dinv * acc + b1)
__global__ void k_finish1(const float* __restrict__ dinv, const float* __restrict__ b1,
                          const float* __restrict__ accb, float* __restrict__ h1) {
    int w = blockIdx.x * blockDim.x + threadIdx.x;
    if (w >= N_NODES * 25) return;
    int i = w / 25, jc = w % 25;
    float di = dinv[i];
    float4 v = ((const float4*)accb)[w];
    float4 b = ((const float4*)b1)[jc];
    float4 o;
    o.x = tanhf(di * v.x + b.x);
    o.y = tanhf(di * v.y + b.y);
    o.z = tanhf(di * v.z + b.z);
    o.w = tanhf(di * v.w + b.w);
    ((float4*)h1)[w] = o;
}

// per node: pool[batch[i]] += dinv[i] * (acc2[i] . Wlin); cnt[batch[i]] += 1
__global__ void k_pool(const float* __restrict__ dinv, const float* __restrict__ accb,
                       const float* __restrict__ Wlin, const int* __restrict__ batch,
                       float* __restrict__ pool, float* __restrict__ cnt) {
    int i = blockIdx.x * blockDim.x + threadIdx.x;
    if (i >= N_NODES) return;
    float di = dinv[i];
    float s = 0.0f;
#pragma unroll
    for (int jc = 0; jc < 25; ++jc) {
        float4 v  = *(const float4*)&accb[i * HID + jc * 4];
        float4 wl = ((const float4*)Wlin)[jc];
        s += v.x * wl.x + v.y * wl.y + v.z * wl.z + v.w * wl.w;
    }
    s *= di;
    int g = batch[i];
    atomicAdd(&pool[g], s);
    atomicAdd(&cnt[g], 1.0f);
}

__global__ void k_final(const float* __restrict__ pool, const float* __restrict__ cnt,
                        const float* __restrict__ b2, const float* __restrict__ Wlin,
                        const float* __restrict__ blin, float* __restrict__ out) {
    int g = threadIdx.x;
    if (g >= N_GRAPHS) return;
    float c2 = 0.0f;
    for (int j = 0; j < HID; ++j) c2 += b2[j] * Wlin[j];
    out[g] = pool[g] / fmaxf(cnt[g], 1.0f) + c2 + blin[0];
}

extern "C" void kernel_launch(void* const* d_in, const int* in_sizes, int n_in,
                              void* d_out, int out_size, void* d_ws, size_t ws_size,
                              hipStream_t stream) {
    const float* x    = (const float*)d_in[0];
    const int*   ei   = (const int*)d_in[1];
    const int*   batch= (const int*)d_in[2];
    const float* W1   = (const float*)d_in[3];
    const float* b1   = (const float*)d_in[4];
    const float* W2   = (const float*)d_in[5];
    const float* b2   = (const float*)d_in[6];
    const float* Wlin = (const float*)d_in[7];
    const float* blin = (const float*)d_in[8];
    float* out = (float*)d_out;

    const int E = in_sizes[1] / 2;
    const int* src = ei;
    const int* dst = ei + E;

    float* ws   = (float*)d_ws;
    float* dinv = ws + OFF_DINV;
    float* cnt  = ws + OFF_CNT;
    float* pool = ws + OFF_POOL;
    float* HS   = ws + OFF_HS;
    float* ACC  = ws + OFF_ACC;
    float* H1   = ws + OFF_H1;

    k_init<<<(N_NODES + 255) / 256, 256, 0, stream>>>(dinv, pool, cnt);
    k_deg<<<(E + 255) / 256, 256, 0, stream>>>(dst, dinv, E);
    k_dinv<<<(N_NODES + 255) / 256, 256, 0, stream>>>(dinv);

    k_gemm<128><<<(N_NODES + 63) / 64, 256, 0, stream>>>(x, W1, dinv, HS, ACC);
    k_scatter<<<(E * 25 + 255) / 256, 256, 0, stream>>>(src, dst, HS, ACC, E);
    k_finish1<<<(N_NODES * 25 + 255) / 256, 256, 0, stream>>>(dinv, b1, ACC, H1);

    k_gemm<100><<<(N_NODES + 63) / 64, 256, 0, stream>>>(H1, W2, dinv, HS, ACC);
    k_scatter<<<(E * 25 + 255) / 256, 256, 0, stream>>>(src, dst, HS, ACC, E);
    k_pool<<<(N_NODES + 255) / 256, 256, 0, stream>>>(dinv, ACC, Wlin, batch, pool, cnt);
    k_final<<<1, 64, 0, stream>>>(pool, cnt, b2, Wlin, blin, out);
}

// Round 2
// 2999.492 us; speedup vs baseline: 3.3327x; 3.3327x over previous
//
#include <hip/hip_runtime.h>
#include <hip/hip_bf16.h>

#define N_NODES 50000
#define N_GRAPHS 64
#define HID 100

// workspace layout (float offsets)
#define OFF_DINV 0
#define OFF_CNT  50048
#define OFF_POOL 50112
#define OFF_HS   50176
#define OFF_ACC  (OFF_HS + N_NODES * HID)
#define OFF_H1   (OFF_ACC + N_NODES * HID)

__global__ void k_init(float* __restrict__ deg, float* __restrict__ pool,
                       float* __restrict__ cnt) {
    int i = blockIdx.x * blockDim.x + threadIdx.x;
    if (i < N_NODES) deg[i] = 1.0f;               // self-loop
    if (i < N_GRAPHS) { pool[i] = 0.0f; cnt[i] = 0.0f; }
}

__global__ void k_deg(const int* __restrict__ dst, float* __restrict__ deg, int E) {
    int e = blockIdx.x * blockDim.x + threadIdx.x;
    if (e < E) atomicAdd(&deg[dst[e]], 1.0f);
}

__global__ void k_dinv(float* __restrict__ d) {
    int i = blockIdx.x * blockDim.x + threadIdx.x;
    if (i < N_NODES) d[i] = rsqrtf(d[i]);         // deg >= 1 always
}

// hs[i][j] = dinv[i] * sum_k X[i][k] * W[k][j]; also written to acc (self-loop init).
// Block: 64 rows x 128 cols (cols 100..127 padded zero). 256 threads, 4x8 per thread.
// __launch_bounds__(256,4): cap VGPR<=128 — round-1 build hit 256 VGPR + scratch
// spill (FETCH/WRITE ~50x ideal). unroll 2 keeps live set ~60 regs.
template<int K>
__global__ __launch_bounds__(256, 4) void k_gemm(const float* __restrict__ X,
                                                 const float* __restrict__ W,
                                                 const float* __restrict__ dinv,
                                                 float* __restrict__ hs,
                                                 float* __restrict__ accb) {
    __shared__ __align__(16) float xs[32][64];    // [k_local][row]
    __shared__ __align__(16) float ws[32][128];   // [k_local][col]
    const int t = threadIdx.x;
    const int base = blockIdx.x * 64;
    const int r0 = (t >> 4) * 4;     // 0..60
    const int c0 = (t & 15) * 8;     // 0..120
    const int f  = t & 7;            // x-stage float4 slot
    const int rr = t >> 3;           // x-stage row 0..31 / w-stage k 0..31
    const int cg = t & 7;            // w-stage col group

    float acc[4][8];
#pragma unroll
    for (int i = 0; i < 4; ++i)
#pragma unroll
        for (int j = 0; j < 8; ++j) acc[i][j] = 0.0f;

    for (int k0 = 0; k0 < K; k0 += 32) {
        // stage X^T tile
#pragma unroll
        for (int p = 0; p < 2; ++p) {
            int r = p * 32 + rr;
            int row = base + r;
#pragma unroll
            for (int u = 0; u < 4; ++u) {
                int k = k0 + 4 * f + u;
                float v = 0.0f;
                if (row < N_NODES && k < K) v = X[row * K + k];
                xs[4 * f + u][r] = v;
            }
        }
        // stage W tile (pad cols >= HID and k >= K with 0)
#pragma unroll
        for (int u = 0; u < 16; ++u) {
            int c = 16 * cg + u;
            int k = k0 + rr;
            float v = 0.0f;
            if (k < K && c < HID) v = W[k * HID + c];
            ws[rr][c] = v;
        }
        __syncthreads();

#pragma unroll 2
        for (int kk = 0; kk < 32; ++kk) {
            const float4 a  = *(const float4*)&xs[kk][r0];
            const float4 w0 = *(const float4*)&ws[kk][c0];
            const float4 w1 = *(const float4*)&ws[kk][c0 + 4];
#pragma unroll
            for (int i = 0; i < 4; ++i) {
                const float ax = (i == 0) ? a.x : (i == 1) ? a.y : (i == 2) ? a.z : a.w;
                acc[i][0] += ax * w0.x;
                acc[i][1] += ax * w0.y;
                acc[i][2] += ax * w0.z;
                acc[i][3] += ax * w0.w;
                acc[i][4] += ax * w1.x;
                acc[i][5] += ax * w1.y;
                acc[i][6] += ax * w1.z;
                acc[i][7] += ax * w1.w;
            }
        }
        __syncthreads();
    }

    // epilogue: scale by dinv, write hs and acc (only cols < HID)
#pragma unroll
    for (int i = 0; i < 4; ++i) {
        int row = base + r0 + i;
        if (row >= N_NODES) continue;
        float di = dinv[row];
        float4 v0 = make_float4(di * acc[i][0], di * acc[i][1], di * acc[i][2], di * acc[i][3]);
        float4 v1 = make_float4(di * acc[i][4], di * acc[i][5], di * acc[i][6], di * acc[i][7]);
        float* hp = hs   + row * HID + c0;
        float* ap = accb + row * HID + c0;
        if (c0 < 96) {
            *(float4*)hp = v0; *(float4*)(hp + 4) = v1;
            *(float4*)ap = v0; *(float4*)(ap + 4) = v1;
        } else if (c0 == 96) {
            *(float4*)hp = v0;
            *(float4*)ap = v0;
        }
    }
}

// acc[dst] += hs[src], 25 float4 chunks per edge
__global__ void k_scatter(const int* __restrict__ src, const int* __restrict__ dst,
                          const float* __restrict__ hs, float* __restrict__ acc, int E) {
    int w = blockIdx.x * blockDim.x + threadIdx.x;
    if (w >= E * 25) return;
    int e = w / 25, jc = w % 25;
    int s = src[e], d = dst[e];
    float4 v = *(const float4*)&hs[s * HID + jc * 4];
    float* a = &acc[d * HID + jc * 4];
    atomicAdd(a + 0, v.x);
    atomicAdd(a + 1, v.y);
    atomicAdd(a + 2, v.z);
    atomicAdd(a + 3, v.w);
}

// h1 = tanh(dinv * acc + b1)
__global__ void k_finish1(const float* __restrict__ dinv, const float* __restrict__ b1,
                          const float* __restrict__ accb, float* __restrict__ h1) {
    int w = blockIdx.x * blockDim.x + threadIdx.x;
    if (w >= N_NODES * 25) return;
    int i = w / 25, jc = w % 25;
    float di = dinv[i];
    float4 v = ((const float4*)accb)[w];
    float4 b = ((const float4*)b1)[jc];
    float4 o;
    o.x = tanhf(di * v.x + b.x);
    o.y = tanhf(di * v.y + b.y);
    o.z = tanhf(di * v.z + b.z);
    o.w = tanhf(di * v.w + b.w);
    ((float4*)h1)[w] = o;
}

// per node: pool[batch[i]] += dinv[i] * (acc2[i] . Wlin); cnt[batch[i]] += 1
__global__ void k_pool(const float* __restrict__ dinv, const float* __restrict__ accb,
                       const float* __restrict__ Wlin, const int* __restrict__ batch,
                       float* __restrict__ pool, float* __restrict__ cnt) {
    int i = blockIdx.x * blockDim.x + threadIdx.x;
    if (i >= N_NODES) return;
    float di = dinv[i];
    float s = 0.0f;
#pragma unroll
    for (int jc = 0; jc < 25; ++jc) {
        float4 v  = *(const float4*)&accb[i * HID + jc * 4];
        float4 wl = ((const float4*)Wlin)[jc];
        s += v.x * wl.x + v.y * wl.y + v.z * wl.z + v.w * wl.w;
    }
    s *= di;
    int g = batch[i];
    atomicAdd(&pool[g], s);
    atomicAdd(&cnt[g], 1.0f);
}

__global__ void k_final(const float* __restrict__ pool, const float* __restrict__ cnt,
                        const float* __restrict__ b2, const float* __restrict__ Wlin,
                        const float* __restrict__ blin, float* __restrict__ out) {
    int g = threadIdx.x;
    if (g >= N_GRAPHS) return;
    float c2 = 0.0f;
    for (int j = 0; j < HID; ++j) c2 += b2[j] * Wlin[j];
    out[g] = pool[g] / fmaxf(cnt[g], 1.0f) + c2 + blin[0];
}

extern "C" void kernel_launch(void* const* d_in, const int* in_sizes, int n_in,
                              void* d_out, int out_size, void* d_ws, size_t ws_size,
                              hipStream_t stream) {
    const float* x    = (const float*)d_in[0];
    const int*   ei   = (const int*)d_in[1];
    const int*   batch= (const int*)d_in[2];
    const float* W1   = (const float*)d_in[3];
    const float* b1   = (const float*)d_in[4];
    const float* W2   = (const float*)d_in[5];
    const float* b2   = (const float*)d_in[6];
    const float* Wlin = (const float*)d_in[7];
    const float* blin = (const float*)d_in[8];
    float* out = (float*)d_out;

    const int E = in_sizes[1] / 2;
    const int* src = ei;
    const int* dst = ei + E;

    float* ws   = (float*)d_ws;
    float* dinv = ws + OFF_DINV;
    float* cnt  = ws + OFF_CNT;
    float* pool = ws + OFF_POOL;
    float* HS   = ws + OFF_HS;
    float* ACC  = ws + OFF_ACC;
    float* H1   = ws + OFF_H1;

    k_init<<<(N_NODES + 255) / 256, 256, 0, stream>>>(dinv, pool, cnt);
    k_deg<<<(E + 255) / 256, 256, 0, stream>>>(dst, dinv, E);
    k_dinv<<<(N_NODES + 255) / 256, 256, 0, stream>>>(dinv);

    k_gemm<128><<<(N_NODES + 63) / 64, 256, 0, stream>>>(x, W1, dinv, HS, ACC);
    k_scatter<<<(E * 25 + 255) / 256, 256, 0, stream>>>(src, dst, HS, ACC, E);
    k_finish1<<<(N_NODES * 25 + 255) / 256, 256, 0, stream>>>(dinv, b1, ACC, H1);

    k_gemm<100><<<(N_NODES + 63) / 64, 256, 0, stream>>>(H1, W2, dinv, HS, ACC);
    k_scatter<<<(E * 25 + 255) / 256, 256, 0, stream>>>(src, dst, HS, ACC, E);
    k_pool<<<(N_NODES + 255) / 256, 256, 0, stream>>>(dinv, ACC, Wlin, batch, pool, cnt);
    k_final<<<1, 64, 0, stream>>>(pool, cnt, b2, Wlin, blin, out);
}

// Round 3
// 796.983 us; speedup vs baseline: 12.5428x; 3.7636x over previous
//
#include <hip/hip_runtime.h>
#include <hip/hip_bf16.h>

#define N_NODES 50000
#define N_GRAPHS 64
#define HID 100

// ---- workspace layout ----
// float region (offsets in floats)
#define OFF_DINV 0
#define OFF_CNTF 50048
#define OFF_POOL 50112
#define OFF_HS   50176
#define OFF_H1   (OFF_HS + N_NODES * HID)            // 5,050,176  (also reused as ACC2)
// int region (offsets in ints from d_ws base)
#define OFF_COUNT  (OFF_H1 + N_NODES * HID)          // 10,050,176
#define OFF_ROWPTR (OFF_COUNT + 50048)               // 10,100,224 (needs N+1)
#define OFF_CURSOR (OFF_ROWPTR + 50056)              // 10,150,280
#define OFF_EIDX   (OFF_CURSOR + 50048)              // 10,200,328 (+E=800k -> ~44 MB total)

__global__ void k_zero(int* __restrict__ count, float* __restrict__ pool,
                       float* __restrict__ cntf) {
    int i = blockIdx.x * blockDim.x + threadIdx.x;
    if (i < N_NODES) count[i] = 0;
    if (i < N_GRAPHS) { pool[i] = 0.0f; cntf[i] = 0.0f; }
}

__global__ void k_hist(const int* __restrict__ dst, int* __restrict__ count, int E) {
    int e = blockIdx.x * blockDim.x + threadIdx.x;
    if (e < E) atomicAdd(&count[dst[e]], 1);
}

__global__ void k_dinv(const int* __restrict__ count, float* __restrict__ dinv) {
    int i = blockIdx.x * blockDim.x + threadIdx.x;
    if (i < N_NODES) dinv[i] = rsqrtf((float)(count[i] + 1));  // +1 self loop
}

// single-block exclusive scan of count[0..N) -> rowptr[0..N], cursor = rowptr copy
#define SCAN_T 1024
__global__ __launch_bounds__(SCAN_T) void k_scan(const int* __restrict__ count,
                                                 int* __restrict__ rowptr,
                                                 int* __restrict__ cursor) {
    __shared__ int part[SCAN_T];
    const int t = threadIdx.x;
    const int CH = (N_NODES + SCAN_T - 1) / SCAN_T;  // 49
    const int beg = t * CH;
    const int end = min(beg + CH, N_NODES);
    int s = 0;
    for (int i = beg; i < end; ++i) s += count[i];
    part[t] = s;
    __syncthreads();
    for (int off = 1; off < SCAN_T; off <<= 1) {
        int v = (t >= off) ? part[t - off] : 0;
        __syncthreads();
        part[t] += v;
        __syncthreads();
    }
    int run = (t == 0) ? 0 : part[t - 1];
    for (int i = beg; i < end; ++i) {
        rowptr[i] = run; cursor[i] = run;
        run += count[i];
    }
    if (t == SCAN_T - 1) rowptr[N_NODES] = run;
}

__global__ void k_fill(const int* __restrict__ src, const int* __restrict__ dst,
                       int* __restrict__ cursor, int* __restrict__ eidx, int E) {
    int e = blockIdx.x * blockDim.x + threadIdx.x;
    if (e < E) {
        int pos = atomicAdd(&cursor[dst[e]], 1);
        eidx[pos] = src[e];
    }
}

// hs[i][j] = dinv[i] * sum_k X[i][k] * W[k][j]
// Block: 64 rows x 128 cols (cols 100..127 padded zero). 256 threads, 4x8 per thread.
// __launch_bounds__(256,4): cap VGPR<=128 (round-1 spilled at 256 VGPR).
template<int K>
__global__ __launch_bounds__(256, 4) void k_gemm(const float* __restrict__ X,
                                                 const float* __restrict__ W,
                                                 const float* __restrict__ dinv,
                                                 float* __restrict__ hs) {
    __shared__ __align__(16) float xs[32][64];    // [k_local][row]
    __shared__ __align__(16) float ws[32][128];   // [k_local][col]
    const int t = threadIdx.x;
    const int base = blockIdx.x * 64;
    const int r0 = (t >> 4) * 4;     // 0..60
    const int c0 = (t & 15) * 8;     // 0..120
    const int f  = t & 7;            // x-stage float4 slot
    const int rr = t >> 3;           // x-stage row 0..31 / w-stage k 0..31
    const int cg = t & 7;            // w-stage col group

    float acc[4][8];
#pragma unroll
    for (int i = 0; i < 4; ++i)
#pragma unroll
        for (int j = 0; j < 8; ++j) acc[i][j] = 0.0f;

    for (int k0 = 0; k0 < K; k0 += 32) {
        // stage X^T tile
#pragma unroll
        for (int p = 0; p < 2; ++p) {
            int r = p * 32 + rr;
            int row = base + r;
#pragma unroll
            for (int u = 0; u < 4; ++u) {
                int k = k0 + 4 * f + u;
                float v = 0.0f;
                if (row < N_NODES && k < K) v = X[row * K + k];
                xs[4 * f + u][r] = v;
            }
        }
        // stage W tile (pad cols >= HID and k >= K with 0)
#pragma unroll
        for (int u = 0; u < 16; ++u) {
            int c = 16 * cg + u;
            int k = k0 + rr;
            float v = 0.0f;
            if (k < K && c < HID) v = W[k * HID + c];
            ws[rr][c] = v;
        }
        __syncthreads();

#pragma unroll 2
        for (int kk = 0; kk < 32; ++kk) {
            const float4 a  = *(const float4*)&xs[kk][r0];
            const float4 w0 = *(const float4*)&ws[kk][c0];
            const float4 w1 = *(const float4*)&ws[kk][c0 + 4];
#pragma unroll
            for (int i = 0; i < 4; ++i) {
                const float ax = (i == 0) ? a.x : (i == 1) ? a.y : (i == 2) ? a.z : a.w;
                acc[i][0] += ax * w0.x;
                acc[i][1] += ax * w0.y;
                acc[i][2] += ax * w0.z;
                acc[i][3] += ax * w0.w;
                acc[i][4] += ax * w1.x;
                acc[i][5] += ax * w1.y;
                acc[i][6] += ax * w1.z;
                acc[i][7] += ax * w1.w;
            }
        }
        __syncthreads();
    }

#pragma unroll
    for (int i = 0; i < 4; ++i) {
        int row = base + r0 + i;
        if (row >= N_NODES) continue;
        float di = dinv[row];
        float4 v0 = make_float4(di * acc[i][0], di * acc[i][1], di * acc[i][2], di * acc[i][3]);
        float4 v1 = make_float4(di * acc[i][4], di * acc[i][5], di * acc[i][6], di * acc[i][7]);
        float* hp = hs + row * HID + c0;
        if (c0 < 96) {
            *(float4*)hp = v0; *(float4*)(hp + 4) = v1;
        } else if (c0 == 96) {
            *(float4*)hp = v0;
        }
    }
}

// layer-1 aggregate+finish: h1[i] = tanh(dinv[i]*(hs[i] + sum_{src in N(i)} hs[src]) + b1)
__global__ void k_gather1(const int* __restrict__ rowptr, const int* __restrict__ eidx,
                          const float* __restrict__ hs, const float* __restrict__ dinv,
                          const float* __restrict__ b1, float* __restrict__ h1) {
    int w = blockIdx.x * blockDim.x + threadIdx.x;
    if (w >= N_NODES * 25) return;
    int i = w / 25, jc = w % 25;
    float4 s = *(const float4*)&hs[i * HID + jc * 4];   // self loop
    int beg = rowptr[i], end = rowptr[i + 1];
    for (int e = beg; e < end; ++e) {
        int sn = eidx[e];
        float4 v = *(const float4*)&hs[sn * HID + jc * 4];
        s.x += v.x; s.y += v.y; s.z += v.z; s.w += v.w;
    }
    float di = dinv[i];
    float4 b = ((const float4*)b1)[jc];
    float4 o;
    o.x = tanhf(di * s.x + b.x);
    o.y = tanhf(di * s.y + b.y);
    o.z = tanhf(di * s.z + b.z);
    o.w = tanhf(di * s.w + b.w);
    ((float4*)h1)[w] = o;
}

// layer-2 aggregate: acc[i] = hs[i] + sum hs[src]   (dinv/b2 applied downstream)
__global__ void k_gather2(const int* __restrict__ rowptr, const int* __restrict__ eidx,
                          const float* __restrict__ hs, float* __restrict__ acc) {
    int w = blockIdx.x * blockDim.x + threadIdx.x;
    if (w >= N_NODES * 25) return;
    int i = w / 25, jc = w % 25;
    float4 s = *(const float4*)&hs[i * HID + jc * 4];
    int beg = rowptr[i], end = rowptr[i + 1];
    for (int e = beg; e < end; ++e) {
        int sn = eidx[e];
        float4 v = *(const float4*)&hs[sn * HID + jc * 4];
        s.x += v.x; s.y += v.y; s.z += v.z; s.w += v.w;
    }
    ((float4*)acc)[w] = s;
}

// per node: pool[batch[i]] += dinv[i] * (acc2[i] . Wlin); cnt[batch[i]] += 1
__global__ void k_pool(const float* __restrict__ dinv, const float* __restrict__ accb,
                       const float* __restrict__ Wlin, const int* __restrict__ batch,
                       float* __restrict__ pool, float* __restrict__ cnt) {
    int i = blockIdx.x * blockDim.x + threadIdx.x;
    if (i >= N_NODES) return;
    float di = dinv[i];
    float s = 0.0f;
#pragma unroll
    for (int jc = 0; jc < 25; ++jc) {
        float4 v  = *(const float4*)&accb[i * HID + jc * 4];
        float4 wl = ((const float4*)Wlin)[jc];
        s += v.x * wl.x + v.y * wl.y + v.z * wl.z + v.w * wl.w;
    }
    s *= di;
    int g = batch[i];
    atomicAdd(&pool[g], s);
    atomicAdd(&cnt[g], 1.0f);
}

__global__ void k_final(const float* __restrict__ pool, const float* __restrict__ cnt,
                        const float* __restrict__ b2, const float* __restrict__ Wlin,
                        const float* __restrict__ blin, float* __restrict__ out) {
    int g = threadIdx.x;
    if (g >= N_GRAPHS) return;
    float c2 = 0.0f;
    for (int j = 0; j < HID; ++j) c2 += b2[j] * Wlin[j];
    out[g] = pool[g] / fmaxf(cnt[g], 1.0f) + c2 + blin[0];
}

extern "C" void kernel_launch(void* const* d_in, const int* in_sizes, int n_in,
                              void* d_out, int out_size, void* d_ws, size_t ws_size,
                              hipStream_t stream) {
    const float* x    = (const float*)d_in[0];
    const int*   ei   = (const int*)d_in[1];
    const int*   batch= (const int*)d_in[2];
    const float* W1   = (const float*)d_in[3];
    const float* b1   = (const float*)d_in[4];
    const float* W2   = (const float*)d_in[5];
    const float* b2   = (const float*)d_in[6];
    const float* Wlin = (const float*)d_in[7];
    const float* blin = (const float*)d_in[8];
    float* out = (float*)d_out;

    const int E = in_sizes[1] / 2;
    const int* src = ei;
    const int* dst = ei + E;

    float* wsf  = (float*)d_ws;
    int*   wsi  = (int*)d_ws;
    float* dinv = wsf + OFF_DINV;
    float* cntf = wsf + OFF_CNTF;
    float* pool = wsf + OFF_POOL;
    float* HS   = wsf + OFF_HS;
    float* H1   = wsf + OFF_H1;          // also ACC2 after gemm2 consumes it
    int* count  = wsi + OFF_COUNT;
    int* rowptr = wsi + OFF_ROWPTR;
    int* cursor = wsi + OFF_CURSOR;
    int* eidx   = wsi + OFF_EIDX;

    // CSR build (dst-grouped) + dinv
    k_zero<<<(N_NODES + 255) / 256, 256, 0, stream>>>(count, pool, cntf);
    k_hist<<<(E + 255) / 256, 256, 0, stream>>>(dst, count, E);
    k_dinv<<<(N_NODES + 255) / 256, 256, 0, stream>>>(count, dinv);
    k_scan<<<1, SCAN_T, 0, stream>>>(count, rowptr, cursor);
    k_fill<<<(E + 255) / 256, 256, 0, stream>>>(src, dst, cursor, eidx, E);

    // layer 1
    k_gemm<128><<<(N_NODES + 63) / 64, 256, 0, stream>>>(x, W1, dinv, HS);
    k_gather1<<<(N_NODES * 25 + 255) / 256, 256, 0, stream>>>(rowptr, eidx, HS, dinv, b1, H1);

    // layer 2
    k_gemm<100><<<(N_NODES + 63) / 64, 256, 0, stream>>>(H1, W2, dinv, HS);
    k_gather2<<<(N_NODES * 25 + 255) / 256, 256, 0, stream>>>(rowptr, eidx, HS, H1);

    // readout
    k_pool<<<(N_NODES + 255) / 256, 256, 0, stream>>>(dinv, H1, Wlin, batch, pool, cntf);
    k_final<<<1, 64, 0, stream>>>(pool, cntf, b2, Wlin, blin, out);
}

// Round 4
// 426.394 us; speedup vs baseline: 23.4441x; 1.8691x over previous
//
#include <hip/hip_runtime.h>
#include <hip/hip_bf16.h>

#define N_NODES 50000
#define N_GRAPHS 64
#define HID 100

// ---- workspace layout ----
// float region (offsets in floats)
#define OFF_DINV 0
#define OFF_CNTF 50048
#define OFF_POOL 50112
#define OFF_HS   50176
#define OFF_H1   (OFF_HS + N_NODES * HID)            // 5,050,176  (also reused as ACC2)
// int region (offsets in ints from d_ws base)
#define OFF_COUNT  (OFF_H1 + N_NODES * HID)          // 10,050,176
#define OFF_ROWPTR (OFF_COUNT + 50048)               // 10,100,224 (needs N+1)
#define OFF_CURSOR (OFF_ROWPTR + 50056)              // 10,150,280
#define OFF_EIDX   (OFF_CURSOR + 50048)              // 10,200,328 (+E=800k -> ~44 MB total)

__global__ void k_zero(int* __restrict__ count, float* __restrict__ pool,
                       float* __restrict__ cntf) {
    int i = blockIdx.x * blockDim.x + threadIdx.x;
    if (i < N_NODES) count[i] = 0;
    if (i < N_GRAPHS) { pool[i] = 0.0f; cntf[i] = 0.0f; }
}

__global__ void k_hist(const int* __restrict__ dst, int* __restrict__ count, int E) {
    int e = blockIdx.x * blockDim.x + threadIdx.x;
    if (e < E) atomicAdd(&count[dst[e]], 1);
}

__global__ void k_dinv(const int* __restrict__ count, float* __restrict__ dinv) {
    int i = blockIdx.x * blockDim.x + threadIdx.x;
    if (i < N_NODES) dinv[i] = rsqrtf((float)(count[i] + 1));  // +1 self loop
}

// single-block exclusive scan of count[0..N) -> rowptr[0..N], cursor = rowptr copy
#define SCAN_T 1024
__global__ __launch_bounds__(SCAN_T) void k_scan(const int* __restrict__ count,
                                                 int* __restrict__ rowptr,
                                                 int* __restrict__ cursor) {
    __shared__ int part[SCAN_T];
    const int t = threadIdx.x;
    const int CH = (N_NODES + SCAN_T - 1) / SCAN_T;  // 49
    const int beg = t * CH;
    const int end = min(beg + CH, N_NODES);
    int s = 0;
    for (int i = beg; i < end; ++i) s += count[i];
    part[t] = s;
    __syncthreads();
    for (int off = 1; off < SCAN_T; off <<= 1) {
        int v = (t >= off) ? part[t - off] : 0;
        __syncthreads();
        part[t] += v;
        __syncthreads();
    }
    int run = (t == 0) ? 0 : part[t - 1];
    for (int i = beg; i < end; ++i) {
        rowptr[i] = run; cursor[i] = run;
        run += count[i];
    }
    if (t == SCAN_T - 1) rowptr[N_NODES] = run;
}

__global__ void k_fill(const int* __restrict__ src, const int* __restrict__ dst,
                       int* __restrict__ cursor, int* __restrict__ eidx, int E) {
    int e = blockIdx.x * blockDim.x + threadIdx.x;
    if (e < E) {
        int pos = atomicAdd(&cursor[dst[e]], 1);
        eidx[pos] = src[e];
    }
}

// hs[i][j] = dinv[i] * sum_k X[i][k] * W[k][j]
// Block: 64 rows x 128 cols (cols 100..127 padded zero). 256 threads, 4x8 per thread.
// __launch_bounds__(256,4): cap VGPR<=128 (round-1 spilled at 256 VGPR).
template<int K>
__global__ __launch_bounds__(256, 4) void k_gemm(const float* __restrict__ X,
                                                 const float* __restrict__ W,
                                                 const float* __restrict__ dinv,
                                                 float* __restrict__ hs) {
    __shared__ __align__(16) float xs[32][64];    // [k_local][row]
    __shared__ __align__(16) float ws[32][128];   // [k_local][col]
    const int t = threadIdx.x;
    const int base = blockIdx.x * 64;
    const int r0 = (t >> 4) * 4;     // 0..60
    const int c0 = (t & 15) * 8;     // 0..120
    const int f  = t & 7;            // x-stage float4 slot
    const int rr = t >> 3;           // x-stage row 0..31 / w-stage k 0..31
    const int cg = t & 7;            // w-stage col group

    float acc[4][8];
#pragma unroll
    for (int i = 0; i < 4; ++i)
#pragma unroll
        for (int j = 0; j < 8; ++j) acc[i][j] = 0.0f;

    for (int k0 = 0; k0 < K; k0 += 32) {
        // stage X^T tile
#pragma unroll
        for (int p = 0; p < 2; ++p) {
            int r = p * 32 + rr;
            int row = base + r;
#pragma unroll
            for (int u = 0; u < 4; ++u) {
                int k = k0 + 4 * f + u;
                float v = 0.0f;
                if (row < N_NODES && k < K) v = X[row * K + k];
                xs[4 * f + u][r] = v;
            }
        }
        // stage W tile (pad cols >= HID and k >= K with 0)
#pragma unroll
        for (int u = 0; u < 16; ++u) {
            int c = 16 * cg + u;
            int k = k0 + rr;
            float v = 0.0f;
            if (k < K && c < HID) v = W[k * HID + c];
            ws[rr][c] = v;
        }
        __syncthreads();

#pragma unroll 2
        for (int kk = 0; kk < 32; ++kk) {
            const float4 a  = *(const float4*)&xs[kk][r0];
            const float4 w0 = *(const float4*)&ws[kk][c0];
            const float4 w1 = *(const float4*)&ws[kk][c0 + 4];
#pragma unroll
            for (int i = 0; i < 4; ++i) {
                const float ax = (i == 0) ? a.x : (i == 1) ? a.y : (i == 2) ? a.z : a.w;
                acc[i][0] += ax * w0.x;
                acc[i][1] += ax * w0.y;
                acc[i][2] += ax * w0.z;
                acc[i][3] += ax * w0.w;
                acc[i][4] += ax * w1.x;
                acc[i][5] += ax * w1.y;
                acc[i][6] += ax * w1.z;
                acc[i][7] += ax * w1.w;
            }
        }
        __syncthreads();
    }

#pragma unroll
    for (int i = 0; i < 4; ++i) {
        int row = base + r0 + i;
        if (row >= N_NODES) continue;
        float di = dinv[row];
        float4 v0 = make_float4(di * acc[i][0], di * acc[i][1], di * acc[i][2], di * acc[i][3]);
        float4 v1 = make_float4(di * acc[i][4], di * acc[i][5], di * acc[i][6], di * acc[i][7]);
        float* hp = hs + row * HID + c0;
        if (c0 < 96) {
            *(float4*)hp = v0; *(float4*)(hp + 4) = v1;
        } else if (c0 == 96) {
            *(float4*)hp = v0;
        }
    }
}

// layer-1 aggregate+finish: h1[i] = tanh(dinv[i]*(hs[i] + sum_{src in N(i)} hs[src]) + b1)
__global__ void k_gather1(const int* __restrict__ rowptr, const int* __restrict__ eidx,
                          const float* __restrict__ hs, const float* __restrict__ dinv,
                          const float* __restrict__ b1, float* __restrict__ h1) {
    int w = blockIdx.x * blockDim.x + threadIdx.x;
    if (w >= N_NODES * 25) return;
    int i = w / 25, jc = w % 25;
    float4 s = *(const float4*)&hs[i * HID + jc * 4];   // self loop
    int beg = rowptr[i], end = rowptr[i + 1];
    for (int e = beg; e < end; ++e) {
        int sn = eidx[e];
        float4 v = *(const float4*)&hs[sn * HID + jc * 4];
        s.x += v.x; s.y += v.y; s.z += v.z; s.w += v.w;
    }
    float di = dinv[i];
    float4 b = ((const float4*)b1)[jc];
    float4 o;
    o.x = tanhf(di * s.x + b.x);
    o.y = tanhf(di * s.y + b.y);
    o.z = tanhf(di * s.z + b.z);
    o.w = tanhf(di * s.w + b.w);
    ((float4*)h1)[w] = o;
}

// layer-2 aggregate: acc[i] = hs[i] + sum hs[src]   (dinv/b2 applied downstream)
__global__ void k_gather2(const int* __restrict__ rowptr, const int* __restrict__ eidx,
                          const float* __restrict__ hs, float* __restrict__ acc) {
    int w = blockIdx.x * blockDim.x + threadIdx.x;
    if (w >= N_NODES * 25) return;
    int i = w / 25, jc = w % 25;
    float4 s = *(const float4*)&hs[i * HID + jc * 4];
    int beg = rowptr[i], end = rowptr[i + 1];
    for (int e = beg; e < end; ++e) {
        int sn = eidx[e];
        float4 v = *(const float4*)&hs[sn * HID + jc * 4];
        s.x += v.x; s.y += v.y; s.z += v.z; s.w += v.w;
    }
    ((float4*)acc)[w] = s;
}

// per node: block-local LDS reduction by graph, then <=64 global atomics per block.
// (round-3: per-node global atomics onto 128 addrs serialized -> 384 us)
__global__ __launch_bounds__(256) void k_pool(const float* __restrict__ dinv,
                                              const float* __restrict__ accb,
                                              const float* __restrict__ Wlin,
                                              const int* __restrict__ batch,
                                              float* __restrict__ pool,
                                              float* __restrict__ cnt) {
    __shared__ float sp[N_GRAPHS];
    __shared__ float sc[N_GRAPHS];
    const int t = threadIdx.x;
    if (t < N_GRAPHS) { sp[t] = 0.0f; sc[t] = 0.0f; }
    __syncthreads();
    int i = blockIdx.x * blockDim.x + t;
    if (i < N_NODES) {
        float di = dinv[i];
        float s = 0.0f;
#pragma unroll
        for (int jc = 0; jc < 25; ++jc) {
            float4 v  = *(const float4*)&accb[i * HID + jc * 4];
            float4 wl = ((const float4*)Wlin)[jc];
            s += v.x * wl.x + v.y * wl.y + v.z * wl.z + v.w * wl.w;
        }
        s *= di;
        int g = batch[i];
        atomicAdd(&sp[g], s);
        atomicAdd(&sc[g], 1.0f);
    }
    __syncthreads();
    if (t < N_GRAPHS && sc[t] != 0.0f) {
        atomicAdd(&pool[t], sp[t]);
        atomicAdd(&cnt[t], sc[t]);
    }
}

__global__ void k_final(const float* __restrict__ pool, const float* __restrict__ cnt,
                        const float* __restrict__ b2, const float* __restrict__ Wlin,
                        const float* __restrict__ blin, float* __restrict__ out) {
    int g = threadIdx.x;
    if (g >= N_GRAPHS) return;
    float c2 = 0.0f;
    for (int j = 0; j < HID; ++j) c2 += b2[j] * Wlin[j];
    out[g] = pool[g] / fmaxf(cnt[g], 1.0f) + c2 + blin[0];
}

extern "C" void kernel_launch(void* const* d_in, const int* in_sizes, int n_in,
                              void* d_out, int out_size, void* d_ws, size_t ws_size,
                              hipStream_t stream) {
    const float* x    = (const float*)d_in[0];
    const int*   ei   = (const int*)d_in[1];
    const int*   batch= (const int*)d_in[2];
    const float* W1   = (const float*)d_in[3];
    const float* b1   = (const float*)d_in[4];
    const float* W2   = (const float*)d_in[5];
    const float* b2   = (const float*)d_in[6];
    const float* Wlin = (const float*)d_in[7];
    const float* blin = (const float*)d_in[8];
    float* out = (float*)d_out;

    const int E = in_sizes[1] / 2;
    const int* src = ei;
    const int* dst = ei + E;

    float* wsf  = (float*)d_ws;
    int*   wsi  = (int*)d_ws;
    float* dinv = wsf + OFF_DINV;
    float* cntf = wsf + OFF_CNTF;
    float* pool = wsf + OFF_POOL;
    float* HS   = wsf + OFF_HS;
    float* H1   = wsf + OFF_H1;          // also ACC2 after gemm2 consumes it
    int* count  = wsi + OFF_COUNT;
    int* rowptr = wsi + OFF_ROWPTR;
    int* cursor = wsi + OFF_CURSOR;
    int* eidx   = wsi + OFF_EIDX;

    // CSR build (dst-grouped) + dinv
    k_zero<<<(N_NODES + 255) / 256, 256, 0, stream>>>(count, pool, cntf);
    k_hist<<<(E + 255) / 256, 256, 0, stream>>>(dst, count, E);
    k_dinv<<<(N_NODES + 255) / 256, 256, 0, stream>>>(count, dinv);
    k_scan<<<1, SCAN_T, 0, stream>>>(count, rowptr, cursor);
    k_fill<<<(E + 255) / 256, 256, 0, stream>>>(src, dst, cursor, eidx, E);

    // layer 1
    k_gemm<128><<<(N_NODES + 63) / 64, 256, 0, stream>>>(x, W1, dinv, HS);
    k_gather1<<<(N_NODES * 25 + 255) / 256, 256, 0, stream>>>(rowptr, eidx, HS, dinv, b1, H1);

    // layer 2
    k_gemm<100><<<(N_NODES + 63) / 64, 256, 0, stream>>>(H1, W2, dinv, HS);
    k_gather2<<<(N_NODES * 25 + 255) / 256, 256, 0, stream>>>(rowptr, eidx, HS, H1);

    // readout
    k_pool<<<(N_NODES + 255) / 256, 256, 0, stream>>>(dinv, H1, Wlin, batch, pool, cntf);
    k_final<<<1, 64, 0, stream>>>(pool, cntf, b2, Wlin, blin, out);
}

// Round 5
// 331.099 us; speedup vs baseline: 30.1916x; 1.2878x over previous
//
#include <hip/hip_runtime.h>
#include <hip/hip_bf16.h>

#define N_NODES 50000
#define N_GRAPHS 64
#define HID 100

// ---- workspace layout ----
// float region (offsets in floats)
#define OFF_DINV 0
#define OFF_CNTF 50048
#define OFF_POOL 50112
#define OFF_HS   50176
#define OFF_H1   (OFF_HS + N_NODES * HID)            // 5,050,176  (also reused as ACC2)
// int region (offsets in ints from d_ws base)
#define OFF_COUNT  (OFF_H1 + N_NODES * HID)          // 10,050,176
#define OFF_ROWPTR (OFF_COUNT + 50048)               // 10,100,224 (needs N+1)
#define OFF_CURSOR (OFF_ROWPTR + 50056)              // 10,150,280
#define OFF_PART   (OFF_CURSOR + 50048)              // 10,200,328 (64 ints)
#define OFF_EIDX   (OFF_PART + 64)                   // 10,200,392 (+E=800k -> ~44 MB total)

#define SCAN_BLOCKS 49   // ceil(50000 / 1024)

__global__ void k_zero(int* __restrict__ count, float* __restrict__ pool,
                       float* __restrict__ cntf) {
    int i = blockIdx.x * blockDim.x + threadIdx.x;
    if (i < N_NODES) count[i] = 0;
    if (i < N_GRAPHS) { pool[i] = 0.0f; cntf[i] = 0.0f; }
}

__global__ void k_hist(const int* __restrict__ dst, int* __restrict__ count, int E) {
    int e = blockIdx.x * blockDim.x + threadIdx.x;
    if (e < E) atomicAdd(&count[dst[e]], 1);
}

// ---- parallel scan (round-4: single-block scan was 110 us at 0.14% occupancy) ----
// Phase A: block b reduces count[b*1024 .. +1023] -> part[b]; also writes dinv.
__global__ __launch_bounds__(256) void k_scan_a(const int* __restrict__ count,
                                                int* __restrict__ part,
                                                float* __restrict__ dinv) {
    __shared__ int red[256];
    const int t = threadIdx.x, b = blockIdx.x;
    const int base = b * 1024 + t * 4;
    int s = 0;
#pragma unroll
    for (int u = 0; u < 4; ++u) {
        int i = base + u;
        if (i < N_NODES) {
            int c = count[i];
            s += c;
            dinv[i] = rsqrtf((float)(c + 1));   // +1 self loop
        }
    }
    red[t] = s;
    __syncthreads();
    for (int off = 128; off > 0; off >>= 1) {
        if (t < off) red[t] += red[t + off];
        __syncthreads();
    }
    if (t == 0) part[b] = red[0];
}

// Phase B: one wave exclusive-scans part[0..SCAN_BLOCKS) in place; writes rowptr[N]=E.
__global__ void k_scan_b(int* __restrict__ part, int* __restrict__ rowptr, int E) {
    const int t = threadIdx.x;              // 64 threads
    int orig = (t < SCAN_BLOCKS) ? part[t] : 0;
    int v = orig;
    for (int off = 1; off < 64; off <<= 1) {
        int u = __shfl_up(v, off);
        if (t >= off) v += u;
    }
    if (t < SCAN_BLOCKS) part[t] = v - orig;   // exclusive
    if (t == 0) rowptr[N_NODES] = E;
}

// Phase C: block b re-reads its counts, local exclusive scan + part[b] offset,
// writes rowptr and cursor.
__global__ __launch_bounds__(256) void k_scan_c(const int* __restrict__ count,
                                                const int* __restrict__ part,
                                                int* __restrict__ rowptr,
                                                int* __restrict__ cursor) {
    __shared__ int ts[256];
    const int t = threadIdx.x, b = blockIdx.x;
    const int base = b * 1024 + t * 4;
    int c[4];
    int s = 0;
#pragma unroll
    for (int u = 0; u < 4; ++u) {
        int i = base + u;
        c[u] = (i < N_NODES) ? count[i] : 0;
        s += c[u];
    }
    ts[t] = s;
    __syncthreads();
    for (int off = 1; off < 256; off <<= 1) {
        int v = (t >= off) ? ts[t - off] : 0;
        __syncthreads();
        ts[t] += v;
        __syncthreads();
    }
    int run = part[b] + ts[t] - s;   // exclusive prefix for this thread's 4 counts
#pragma unroll
    for (int u = 0; u < 4; ++u) {
        int i = base + u;
        if (i < N_NODES) { rowptr[i] = run; cursor[i] = run; run += c[u]; }
    }
}

__global__ void k_fill(const int* __restrict__ src, const int* __restrict__ dst,
                       int* __restrict__ cursor, int* __restrict__ eidx, int E) {
    int e = blockIdx.x * blockDim.x + threadIdx.x;
    if (e < E) {
        int pos = atomicAdd(&cursor[dst[e]], 1);
        eidx[pos] = src[e];
    }
}

// hs[i][j] = dinv[i] * sum_k X[i][k] * W[k][j]
// Block: 64 rows x 128 cols (cols 100..127 padded zero). 256 threads, 4x8 per thread.
// __launch_bounds__(256,4): cap VGPR<=128 (round-1 spilled at 256 VGPR).
template<int K>
__global__ __launch_bounds__(256, 4) void k_gemm(const float* __restrict__ X,
                                                 const float* __restrict__ W,
                                                 const float* __restrict__ dinv,
                                                 float* __restrict__ hs) {
    __shared__ __align__(16) float xs[32][64];    // [k_local][row]
    __shared__ __align__(16) float ws[32][128];   // [k_local][col]
    const int t = threadIdx.x;
    const int base = blockIdx.x * 64;
    const int r0 = (t >> 4) * 4;     // 0..60
    const int c0 = (t & 15) * 8;     // 0..120
    const int f  = t & 7;            // x-stage float4 slot
    const int rr = t >> 3;           // x-stage row 0..31 / w-stage k 0..31
    const int cg = t & 7;            // w-stage col group

    float acc[4][8];
#pragma unroll
    for (int i = 0; i < 4; ++i)
#pragma unroll
        for (int j = 0; j < 8; ++j) acc[i][j] = 0.0f;

    for (int k0 = 0; k0 < K; k0 += 32) {
        // stage X^T tile
#pragma unroll
        for (int p = 0; p < 2; ++p) {
            int r = p * 32 + rr;
            int row = base + r;
#pragma unroll
            for (int u = 0; u < 4; ++u) {
                int k = k0 + 4 * f + u;
                float v = 0.0f;
                if (row < N_NODES && k < K) v = X[row * K + k];
                xs[4 * f + u][r] = v;
            }
        }
        // stage W tile (pad cols >= HID and k >= K with 0)
#pragma unroll
        for (int u = 0; u < 16; ++u) {
            int c = 16 * cg + u;
            int k = k0 + rr;
            float v = 0.0f;
            if (k < K && c < HID) v = W[k * HID + c];
            ws[rr][c] = v;
        }
        __syncthreads();

#pragma unroll 2
        for (int kk = 0; kk < 32; ++kk) {
            const float4 a  = *(const float4*)&xs[kk][r0];
            const float4 w0 = *(const float4*)&ws[kk][c0];
            const float4 w1 = *(const float4*)&ws[kk][c0 + 4];
#pragma unroll
            for (int i = 0; i < 4; ++i) {
                const float ax = (i == 0) ? a.x : (i == 1) ? a.y : (i == 2) ? a.z : a.w;
                acc[i][0] += ax * w0.x;
                acc[i][1] += ax * w0.y;
                acc[i][2] += ax * w0.z;
                acc[i][3] += ax * w0.w;
                acc[i][4] += ax * w1.x;
                acc[i][5] += ax * w1.y;
                acc[i][6] += ax * w1.z;
                acc[i][7] += ax * w1.w;
            }
        }
        __syncthreads();
    }

#pragma unroll
    for (int i = 0; i < 4; ++i) {
        int row = base + r0 + i;
        if (row >= N_NODES) continue;
        float di = dinv[row];
        float4 v0 = make_float4(di * acc[i][0], di * acc[i][1], di * acc[i][2], di * acc[i][3]);
        float4 v1 = make_float4(di * acc[i][4], di * acc[i][5], di * acc[i][6], di * acc[i][7]);
        float* hp = hs + row * HID + c0;
        if (c0 < 96) {
            *(float4*)hp = v0; *(float4*)(hp + 4) = v1;
        } else if (c0 == 96) {
            *(float4*)hp = v0;
        }
    }
}

// layer-1 aggregate+finish: h1[i] = tanh(dinv[i]*(hs[i] + sum_{src in N(i)} hs[src]) + b1)
__global__ void k_gather1(const int* __restrict__ rowptr, const int* __restrict__ eidx,
                          const float* __restrict__ hs, const float* __restrict__ dinv,
                          const float* __restrict__ b1, float* __restrict__ h1) {
    int w = blockIdx.x * blockDim.x + threadIdx.x;
    if (w >= N_NODES * 25) return;
    int i = w / 25, jc = w % 25;
    float4 s = *(const float4*)&hs[i * HID + jc * 4];   // self loop
    int beg = rowptr[i], end = rowptr[i + 1];
    for (int e = beg; e < end; ++e) {
        int sn = eidx[e];
        float4 v = *(const float4*)&hs[sn * HID + jc * 4];
        s.x += v.x; s.y += v.y; s.z += v.z; s.w += v.w;
    }
    float di = dinv[i];
    float4 b = ((const float4*)b1)[jc];
    float4 o;
    o.x = tanhf(di * s.x + b.x);
    o.y = tanhf(di * s.y + b.y);
    o.z = tanhf(di * s.z + b.z);
    o.w = tanhf(di * s.w + b.w);
    ((float4*)h1)[w] = o;
}

// layer-2 aggregate: acc[i] = hs[i] + sum hs[src]   (dinv/b2 applied downstream)
__global__ void k_gather2(const int* __restrict__ rowptr, const int* __restrict__ eidx,
                          const float* __restrict__ hs, float* __restrict__ acc) {
    int w = blockIdx.x * blockDim.x + threadIdx.x;
    if (w >= N_NODES * 25) return;
    int i = w / 25, jc = w % 25;
    float4 s = *(const float4*)&hs[i * HID + jc * 4];
    int beg = rowptr[i], end = rowptr[i + 1];
    for (int e = beg; e < end; ++e) {
        int sn = eidx[e];
        float4 v = *(const float4*)&hs[sn * HID + jc * 4];
        s.x += v.x; s.y += v.y; s.z += v.z; s.w += v.w;
    }
    ((float4*)acc)[w] = s;
}

// per node: block-local LDS reduction by graph, then <=64 global atomics per block.
// (round-3: per-node global atomics onto 128 addrs serialized -> 384 us)
__global__ __launch_bounds__(256) void k_pool(const float* __restrict__ dinv,
                                              const float* __restrict__ accb,
                                              const float* __restrict__ Wlin,
                                              const int* __restrict__ batch,
                                              float* __restrict__ pool,
                                              float* __restrict__ cnt) {
    __shared__ float sp[N_GRAPHS];
    __shared__ float sc[N_GRAPHS];
    const int t = threadIdx.x;
    if (t < N_GRAPHS) { sp[t] = 0.0f; sc[t] = 0.0f; }
    __syncthreads();
    int i = blockIdx.x * blockDim.x + t;
    if (i < N_NODES) {
        float di = dinv[i];
        float s = 0.0f;
#pragma unroll
        for (int jc = 0; jc < 25; ++jc) {
            float4 v  = *(const float4*)&accb[i * HID + jc * 4];
            float4 wl = ((const float4*)Wlin)[jc];
            s += v.x * wl.x + v.y * wl.y + v.z * wl.z + v.w * wl.w;
        }
        s *= di;
        int g = batch[i];
        atomicAdd(&sp[g], s);
        atomicAdd(&sc[g], 1.0f);
    }
    __syncthreads();
    if (t < N_GRAPHS && sc[t] != 0.0f) {
        atomicAdd(&pool[t], sp[t]);
        atomicAdd(&cnt[t], sc[t]);
    }
}

__global__ void k_final(const float* __restrict__ pool, const float* __restrict__ cnt,
                        const float* __restrict__ b2, const float* __restrict__ Wlin,
                        const float* __restrict__ blin, float* __restrict__ out) {
    int g = threadIdx.x;
    if (g >= N_GRAPHS) return;
    float c2 = 0.0f;
    for (int j = 0; j < HID; ++j) c2 += b2[j] * Wlin[j];
    out[g] = pool[g] / fmaxf(cnt[g], 1.0f) + c2 + blin[0];
}

extern "C" void kernel_launch(void* const* d_in, const int* in_sizes, int n_in,
                              void* d_out, int out_size, void* d_ws, size_t ws_size,
                              hipStream_t stream) {
    const float* x    = (const float*)d_in[0];
    const int*   ei   = (const int*)d_in[1];
    const int*   batch= (const int*)d_in[2];
    const float* W1   = (const float*)d_in[3];
    const float* b1   = (const float*)d_in[4];
    const float* W2   = (const float*)d_in[5];
    const float* b2   = (const float*)d_in[6];
    const float* Wlin = (const float*)d_in[7];
    const float* blin = (const float*)d_in[8];
    float* out = (float*)d_out;

    const int E = in_sizes[1] / 2;
    const int* src = ei;
    const int* dst = ei + E;

    float* wsf  = (float*)d_ws;
    int*   wsi  = (int*)d_ws;
    float* dinv = wsf + OFF_DINV;
    float* cntf = wsf + OFF_CNTF;
    float* pool = wsf + OFF_POOL;
    float* HS   = wsf + OFF_HS;
    float* H1   = wsf + OFF_H1;          // also ACC2 after gemm2 consumes it
    int* count  = wsi + OFF_COUNT;
    int* rowptr = wsi + OFF_ROWPTR;
    int* cursor = wsi + OFF_CURSOR;
    int* part   = wsi + OFF_PART;
    int* eidx   = wsi + OFF_EIDX;

    // CSR build (dst-grouped) + dinv
    k_zero<<<(N_NODES + 255) / 256, 256, 0, stream>>>(count, pool, cntf);
    k_hist<<<(E + 255) / 256, 256, 0, stream>>>(dst, count, E);
    k_scan_a<<<SCAN_BLOCKS, 256, 0, stream>>>(count, part, dinv);
    k_scan_b<<<1, 64, 0, stream>>>(part, rowptr, E);
    k_scan_c<<<SCAN_BLOCKS, 256, 0, stream>>>(count, part, rowptr, cursor);
    k_fill<<<(E + 255) / 256, 256, 0, stream>>>(src, dst, cursor, eidx, E);

    // layer 1
    k_gemm<128><<<(N_NODES + 63) / 64, 256, 0, stream>>>(x, W1, dinv, HS);
    k_gather1<<<(N_NODES * 25 + 255) / 256, 256, 0, stream>>>(rowptr, eidx, HS, dinv, b1, H1);

    // layer 2
    k_gemm<100><<<(N_NODES + 63) / 64, 256, 0, stream>>>(H1, W2, dinv, HS);
    k_gather2<<<(N_NODES * 25 + 255) / 256, 256, 0, stream>>>(rowptr, eidx, HS, H1);

    // readout
    k_pool<<<(N_NODES + 255) / 256, 256, 0, stream>>>(dinv, H1, Wlin, batch, pool, cntf);
    k_final<<<1, 64, 0, stream>>>(pool, cntf, b2, Wlin, blin, out);
}

// Round 6
// 243.927 us; speedup vs baseline: 40.9813x; 1.3574x over previous
//
#include <hip/hip_runtime.h>
#include <hip/hip_bf16.h>

#define N_NODES 50000
#define N_GRAPHS 64
#define HID 100
#define HP 104            // padded bf16 row stride (13 * 8)

// ---- workspace layout (float offsets) ----
#define OFF_DINV 0
#define OFF_CNTF 50048
#define OFF_POOL 50112
#define OFF_WT1  50176                    // bf16 [112][128] = 7168 floats
#define OFF_WT2  57344
#define OFF_HS   64512                    // bf16 [N][104] = 2.6M floats
#define OFF_H1   2664512                  // bf16 [N][104]
#define OFF_ACC  5264512                  // bf16 [N][104]
#define OFF_COUNT  7864512
#define OFF_ROWPTR 7914560                // N+1
#define OFF_CURSOR 7964616
#define OFF_PART   8014664
#define OFF_EIDX   8014728                // + E (800k)  -> ~35.3 MB total

#define SCAN_BLOCKS 49   // ceil(50000 / 1024)

typedef __attribute__((ext_vector_type(8))) short short8;
typedef __attribute__((ext_vector_type(4))) float floatx4;

__device__ inline float b2f(unsigned int u) {
    union { unsigned int v; float f; } x; x.v = u << 16; return x.f;
}
__device__ inline unsigned short f2b(float f) {
    union { float f; unsigned int v; } x; x.f = f;
    unsigned int r = (x.v + 0x7fffu + ((x.v >> 16) & 1u)) >> 16;   // RTNE
    return (unsigned short)r;
}

__global__ void k_zero(int* __restrict__ count, float* __restrict__ pool,
                       float* __restrict__ cntf) {
    int i = blockIdx.x * blockDim.x + threadIdx.x;
    if (i < N_NODES) count[i] = 0;
    if (i < N_GRAPHS) { pool[i] = 0.0f; cntf[i] = 0.0f; }
}

__global__ void k_hist(const int* __restrict__ dst, int* __restrict__ count, int E) {
    int e = blockIdx.x * blockDim.x + threadIdx.x;
    if (e < E) atomicAdd(&count[dst[e]], 1);
}

// W [KSRC][100] f32 -> Wt [112][128] bf16 (transposed, zero-padded)
__global__ void k_wt(const float* __restrict__ W, int KSRC, unsigned short* __restrict__ Wt) {
    int idx = blockIdx.x * 256 + threadIdx.x;
    if (idx >= 112 * 128) return;
    int c = idx >> 7, k = idx & 127;
    float v = (k < KSRC && c < HID) ? W[k * HID + c] : 0.0f;
    Wt[c * 128 + k] = f2b(v);
}

// ---- parallel scan over counts ----
__global__ __launch_bounds__(256) void k_scan_a(const int* __restrict__ count,
                                                int* __restrict__ part,
                                                float* __restrict__ dinv) {
    __shared__ int red[256];
    const int t = threadIdx.x, b = blockIdx.x;
    const int base = b * 1024 + t * 4;
    int s = 0;
#pragma unroll
    for (int u = 0; u < 4; ++u) {
        int i = base + u;
        if (i < N_NODES) {
            int c = count[i];
            s += c;
            dinv[i] = rsqrtf((float)(c + 1));
        }
    }
    red[t] = s;
    __syncthreads();
    for (int off = 128; off > 0; off >>= 1) {
        if (t < off) red[t] += red[t + off];
        __syncthreads();
    }
    if (t == 0) part[b] = red[0];
}

__global__ void k_scan_b(int* __restrict__ part, int* __restrict__ rowptr, int E) {
    const int t = threadIdx.x;              // 64
    int orig = (t < SCAN_BLOCKS) ? part[t] : 0;
    int v = orig;
    for (int off = 1; off < 64; off <<= 1) {
        int u = __shfl_up(v, off);
        if (t >= off) v += u;
    }
    if (t < SCAN_BLOCKS) part[t] = v - orig;
    if (t == 0) rowptr[N_NODES] = E;
}

__global__ __launch_bounds__(256) void k_scan_c(const int* __restrict__ count,
                                                const int* __restrict__ part,
                                                int* __restrict__ rowptr,
                                                int* __restrict__ cursor) {
    __shared__ int ts[256];
    const int t = threadIdx.x, b = blockIdx.x;
    const int base = b * 1024 + t * 4;
    int c[4];
    int s = 0;
#pragma unroll
    for (int u = 0; u < 4; ++u) {
        int i = base + u;
        c[u] = (i < N_NODES) ? count[i] : 0;
        s += c[u];
    }
    ts[t] = s;
    __syncthreads();
    for (int off = 1; off < 256; off <<= 1) {
        int v = (t >= off) ? ts[t - off] : 0;
        __syncthreads();
        ts[t] += v;
        __syncthreads();
    }
    int run = part[b] + ts[t] - s;
#pragma unroll
    for (int u = 0; u < 4; ++u) {
        int i = base + u;
        if (i < N_NODES) { rowptr[i] = run; cursor[i] = run; run += c[u]; }
    }
}

__global__ void k_fill(const int* __restrict__ src, const int* __restrict__ dst,
                       int* __restrict__ cursor, int* __restrict__ eidx, int E) {
    int e = blockIdx.x * blockDim.x + threadIdx.x;
    if (e < E) {
        int pos = atomicAdd(&cursor[dst[e]], 1);
        eidx[pos] = src[e];
    }
}

// MFMA bf16 GEMM: out[i][c] = f2b(dinv[i] * sum_k A[i][k] * W[k][c]), out [N][HP] bf16.
// Block: 64 rows (4 waves x 16), 112 cols (7 MFMA tiles), K padded to 128.
// A/B frag (16x16x32): row/col = lane&15, k = 8*(lane>>4)+j ; C/D: col=lane&15, row=4*(lane>>4)+r.
template<bool ABF16>
__global__ __launch_bounds__(256) void k_gemm(const void* __restrict__ Asrc,
                                              const unsigned short* __restrict__ Wt, // [112][128]
                                              const float* __restrict__ dinv,
                                              unsigned short* __restrict__ out) {
    __shared__ __align__(16) unsigned short xs[64][136];   // A tile bf16, 272B rows (17x16)
    __shared__ __align__(16) unsigned short ws[112][136];  // B tile bf16 [col][k]
    const int t = threadIdx.x;
    const int base = blockIdx.x * 64;

    // stage Wt -> ws (rows are 64 uints in global, 68 in LDS)
    for (int idx = t; idx < 112 * 64; idx += 256) {
        int c = idx >> 6, u = idx & 63;
        *(unsigned int*)&ws[c][2 * u] = ((const unsigned int*)Wt)[idx];
    }
    // stage A -> xs
    if (ABF16) {
        const unsigned short* A = (const unsigned short*)Asrc;   // [N][HP] bf16
        for (int idx = t; idx < 64 * 16; idx += 256) {
            int r = idx >> 4, q = idx & 15;
            int row = base + r;
            uint4 v = make_uint4(0, 0, 0, 0);
            if (q < 13 && row < N_NODES)
                v = ((const uint4*)(A + (size_t)row * HP))[q];
            *(uint4*)&xs[r][8 * q] = v;
        }
    } else {
        const float* A = (const float*)Asrc;                     // [N][128] f32
        for (int idx = t; idx < 64 * 32; idx += 256) {
            int r = idx >> 5, q = idx & 31;
            int row = base + r;
            ushort4 p;
            if (row < N_NODES) {
                float4 v = ((const float4*)(A + (size_t)row * 128))[q];
                p.x = f2b(v.x); p.y = f2b(v.y); p.z = f2b(v.z); p.w = f2b(v.w);
            } else p = make_ushort4(0, 0, 0, 0);
            *(ushort4*)&xs[r][4 * q] = p;
        }
    }
    __syncthreads();

    const int lane = t & 63, w = t >> 6;
    const int g = lane >> 4, cl = lane & 15;

    floatx4 acc[7];
#pragma unroll
    for (int n = 0; n < 7; ++n) acc[n] = (floatx4){0.f, 0.f, 0.f, 0.f};

#pragma unroll
    for (int kc = 0; kc < 4; ++kc) {
        short8 a = *(const short8*)&xs[w * 16 + cl][kc * 32 + 8 * g];
#pragma unroll
        for (int n = 0; n < 7; ++n) {
            short8 b = *(const short8*)&ws[n * 16 + cl][kc * 32 + 8 * g];
            acc[n] = __builtin_amdgcn_mfma_f32_16x16x32_bf16(a, b, acc[n], 0, 0, 0);
        }
    }

    float di[4]; int grows[4];
#pragma unroll
    for (int r = 0; r < 4; ++r) {
        grows[r] = base + w * 16 + 4 * g + r;
        di[r] = (grows[r] < N_NODES) ? dinv[grows[r]] : 0.0f;
    }
#pragma unroll
    for (int n = 0; n < 7; ++n) {
        int gcol = n * 16 + cl;
        if (gcol >= HP) continue;
#pragma unroll
        for (int r = 0; r < 4; ++r) {
            if (grows[r] < N_NODES)
                out[(size_t)grows[r] * HP + gcol] = f2b(acc[n][r] * di[r]);
        }
    }
}

// layer-1 aggregate+finish: h1 = tanh(dinv*(hs_self + sum hs[src]) + b1), bf16 in/out.
// thread = (node, 8-col chunk), 13 chunks/node.
__global__ void k_gather1(const int* __restrict__ rowptr, const int* __restrict__ eidx,
                          const unsigned short* __restrict__ hs, const float* __restrict__ dinv,
                          const float* __restrict__ b1, unsigned short* __restrict__ h1) {
    int w = blockIdx.x * blockDim.x + threadIdx.x;
    if (w >= N_NODES * 13) return;
    int i = w / 13, c = w % 13;
    const int c0 = 8 * c;
    float s[8];
    uint4 sv = *(const uint4*)(hs + (size_t)i * HP + c0);
    s[0] = b2f(sv.x & 0xffff); s[1] = b2f(sv.x >> 16);
    s[2] = b2f(sv.y & 0xffff); s[3] = b2f(sv.y >> 16);
    s[4] = b2f(sv.z & 0xffff); s[5] = b2f(sv.z >> 16);
    s[6] = b2f(sv.w & 0xffff); s[7] = b2f(sv.w >> 16);
    int beg = rowptr[i], end = rowptr[i + 1];
    for (int e = beg; e < end; ++e) {
        int sn = eidx[e];
        uint4 v = *(const uint4*)(hs + (size_t)sn * HP + c0);
        s[0] += b2f(v.x & 0xffff); s[1] += b2f(v.x >> 16);
        s[2] += b2f(v.y & 0xffff); s[3] += b2f(v.y >> 16);
        s[4] += b2f(v.z & 0xffff); s[5] += b2f(v.z >> 16);
        s[6] += b2f(v.w & 0xffff); s[7] += b2f(v.w >> 16);
    }
    float di = dinv[i];
    unsigned short o[8];
    if (c < 12) {
#pragma unroll
        for (int j = 0; j < 8; ++j) o[j] = f2b(tanhf(di * s[j] + b1[c0 + j]));
    } else {
#pragma unroll
        for (int j = 0; j < 4; ++j) o[j] = f2b(tanhf(di * s[j] + b1[96 + j]));
#pragma unroll
        for (int j = 4; j < 8; ++j) o[j] = 0;   // pad cols 100..103 must be exact 0
    }
    uint4 ov;
    ov.x = (unsigned int)o[0] | ((unsigned int)o[1] << 16);
    ov.y = (unsigned int)o[2] | ((unsigned int)o[3] << 16);
    ov.z = (unsigned int)o[4] | ((unsigned int)o[5] << 16);
    ov.w = (unsigned int)o[6] | ((unsigned int)o[7] << 16);
    *(uint4*)(h1 + (size_t)i * HP + c0) = ov;
}

// layer-2 aggregate: acc = hs_self + sum hs[src] (bf16 in/out; dinv/b2 downstream)
__global__ void k_gather2(const int* __restrict__ rowptr, const int* __restrict__ eidx,
                          const unsigned short* __restrict__ hs, unsigned short* __restrict__ acc) {
    int w = blockIdx.x * blockDim.x + threadIdx.x;
    if (w >= N_NODES * 13) return;
    int i = w / 13, c = w % 13;
    const int c0 = 8 * c;
    float s[8];
    uint4 sv = *(const uint4*)(hs + (size_t)i * HP + c0);
    s[0] = b2f(sv.x & 0xffff); s[1] = b2f(sv.x >> 16);
    s[2] = b2f(sv.y & 0xffff); s[3] = b2f(sv.y >> 16);
    s[4] = b2f(sv.z & 0xffff); s[5] = b2f(sv.z >> 16);
    s[6] = b2f(sv.w & 0xffff); s[7] = b2f(sv.w >> 16);
    int beg = rowptr[i], end = rowptr[i + 1];
    for (int e = beg; e < end; ++e) {
        int sn = eidx[e];
        uint4 v = *(const uint4*)(hs + (size_t)sn * HP + c0);
        s[0] += b2f(v.x & 0xffff); s[1] += b2f(v.x >> 16);
        s[2] += b2f(v.y & 0xffff); s[3] += b2f(v.y >> 16);
        s[4] += b2f(v.z & 0xffff); s[5] += b2f(v.z >> 16);
        s[6] += b2f(v.w & 0xffff); s[7] += b2f(v.w >> 16);
    }
    uint4 ov;
    ov.x = (unsigned int)f2b(s[0]) | ((unsigned int)f2b(s[1]) << 16);
    ov.y = (unsigned int)f2b(s[2]) | ((unsigned int)f2b(s[3]) << 16);
    ov.z = (unsigned int)f2b(s[4]) | ((unsigned int)f2b(s[5]) << 16);
    ov.w = (unsigned int)f2b(s[6]) | ((unsigned int)f2b(s[7]) << 16);
    *(uint4*)(acc + (size_t)i * HP + c0) = ov;
}

// per node: block-local LDS reduction by graph, then <=64 global atomics per block.
__global__ __launch_bounds__(256) void k_pool(const float* __restrict__ dinv,
                                              const unsigned short* __restrict__ accb,
                                              const float* __restrict__ Wlin,
                                              const int* __restrict__ batch,
                                              float* __restrict__ pool,
                                              float* __restrict__ cnt) {
    __shared__ float sp[N_GRAPHS];
    __shared__ float sc[N_GRAPHS];
    const int t = threadIdx.x;
    if (t < N_GRAPHS) { sp[t] = 0.0f; sc[t] = 0.0f; }
    __syncthreads();
    int i = blockIdx.x * blockDim.x + t;
    if (i < N_NODES) {
        float di = dinv[i];
        float s = 0.0f;
#pragma unroll
        for (int jc = 0; jc < 25; ++jc) {
            uint2 v = *(const uint2*)(accb + (size_t)i * HP + 4 * jc);
            float4 wl = ((const float4*)Wlin)[jc];
            s += b2f(v.x & 0xffff) * wl.x + b2f(v.x >> 16) * wl.y
               + b2f(v.y & 0xffff) * wl.z + b2f(v.y >> 16) * wl.w;
        }
        s *= di;
        int g = batch[i];
        atomicAdd(&sp[g], s);
        atomicAdd(&sc[g], 1.0f);
    }
    __syncthreads();
    if (t < N_GRAPHS && sc[t] != 0.0f) {
        atomicAdd(&pool[t], sp[t]);
        atomicAdd(&cnt[t], sc[t]);
    }
}

__global__ void k_final(const float* __restrict__ pool, const float* __restrict__ cnt,
                        const float* __restrict__ b2, const float* __restrict__ Wlin,
                        const float* __restrict__ blin, float* __restrict__ out) {
    int g = threadIdx.x;
    if (g >= N_GRAPHS) return;
    float c2 = 0.0f;
    for (int j = 0; j < HID; ++j) c2 += b2[j] * Wlin[j];
    out[g] = pool[g] / fmaxf(cnt[g], 1.0f) + c2 + blin[0];
}

extern "C" void kernel_launch(void* const* d_in, const int* in_sizes, int n_in,
                              void* d_out, int out_size, void* d_ws, size_t ws_size,
                              hipStream_t stream) {
    const float* x    = (const float*)d_in[0];
    const int*   ei   = (const int*)d_in[1];
    const int*   batch= (const int*)d_in[2];
    const float* W1   = (const float*)d_in[3];
    const float* b1   = (const float*)d_in[4];
    const float* W2   = (const float*)d_in[5];
    const float* b2   = (const float*)d_in[6];
    const float* Wlin = (const float*)d_in[7];
    const float* blin = (const float*)d_in[8];
    float* out = (float*)d_out;

    const int E = in_sizes[1] / 2;
    const int* src = ei;
    const int* dst = ei + E;

    float* wsf  = (float*)d_ws;
    int*   wsi  = (int*)d_ws;
    float* dinv = wsf + OFF_DINV;
    float* cntf = wsf + OFF_CNTF;
    float* pool = wsf + OFF_POOL;
    unsigned short* Wt1 = (unsigned short*)(wsf + OFF_WT1);
    unsigned short* Wt2 = (unsigned short*)(wsf + OFF_WT2);
    unsigned short* HS  = (unsigned short*)(wsf + OFF_HS);
    unsigned short* H1  = (unsigned short*)(wsf + OFF_H1);
    unsigned short* ACC = (unsigned short*)(wsf + OFF_ACC);
    int* count  = wsi + OFF_COUNT;
    int* rowptr = wsi + OFF_ROWPTR;
    int* cursor = wsi + OFF_CURSOR;
    int* part   = wsi + OFF_PART;
    int* eidx   = wsi + OFF_EIDX;

    // CSR build + dinv + weight transposes
    k_zero<<<(N_NODES + 255) / 256, 256, 0, stream>>>(count, pool, cntf);
    k_wt<<<56, 256, 0, stream>>>(W1, 128, Wt1);
    k_wt<<<56, 256, 0, stream>>>(W2, 100, Wt2);
    k_hist<<<(E + 255) / 256, 256, 0, stream>>>(dst, count, E);
    k_scan_a<<<SCAN_BLOCKS, 256, 0, stream>>>(count, part, dinv);
    k_scan_b<<<1, 64, 0, stream>>>(part, rowptr, E);
    k_scan_c<<<SCAN_BLOCKS, 256, 0, stream>>>(count, part, rowptr, cursor);
    k_fill<<<(E + 255) / 256, 256, 0, stream>>>(src, dst, cursor, eidx, E);

    // layer 1
    k_gemm<false><<<(N_NODES + 63) / 64, 256, 0, stream>>>(x, Wt1, dinv, HS);
    k_gather1<<<(N_NODES * 13 + 255) / 256, 256, 0, stream>>>(rowptr, eidx, HS, dinv, b1, H1);

    // layer 2
    k_gemm<true><<<(N_NODES + 63) / 64, 256, 0, stream>>>(H1, Wt2, dinv, HS);
    k_gather2<<<(N_NODES * 13 + 255) / 256, 256, 0, stream>>>(rowptr, eidx, HS, ACC);

    // readout
    k_pool<<<(N_NODES + 255) / 256, 256, 0, stream>>>(dinv, ACC, Wlin, batch, pool, cntf);
    k_final<<<1, 64, 0, stream>>>(pool, cntf, b2, Wlin, blin, out);
}

// Round 7
// 222.991 us; speedup vs baseline: 44.8288x; 1.0939x over previous
//
#include <hip/hip_runtime.h>
#include <hip/hip_bf16.h>

#define N_NODES 50000
#define N_GRAPHS 64
#define HID 100
#define HP 104            // padded bf16 row stride (13 * 8)

#define BKE  4096         // edges per block in p1/p3
#define NBIN 196          // buckets of 256 nodes: ceil(50000/256)
#define MAXBLK 256        // max edge-blocks supported (E <= 1M)

// ---- workspace layout (float offsets) ----
#define OFF_DINV 0
#define OFF_CNTF 50048
#define OFF_POOL 50112
#define OFF_WT1  50176                    // bf16 [112][128] = 7168 floats
#define OFF_WT2  57344
#define OFF_HS   64512                    // bf16 [N][104] = 2.6M floats
#define OFF_H1   2664512                  // bf16 [N][104]
#define OFF_ACC  5264512                  // bf16 [N][104]
#define OFF_ROWPTR 7864512                // N+1 ints
#define OFF_EIDX   7914560                // E ints
#define OFF_BE     8714560                // E uints (packed (src<<16)|dst, bucketed)
#define OFF_BBINS  9514560                // [MAXBLK][NBIN] ints
#define OFF_BOFF   9565760                // [MAXBLK][NBIN] ints
#define OFF_BBASE  9616960                // NBIN+1 ints
// end ~9,617,472 floats = 38.5 MB

typedef __attribute__((ext_vector_type(8))) short short8;
typedef __attribute__((ext_vector_type(4))) float floatx4;

__device__ inline float b2f(unsigned int u) {
    union { unsigned int v; float f; } x; x.v = u << 16; return x.f;
}
__device__ inline unsigned short f2b(float f) {
    union { float f; unsigned int v; } x; x.f = f;
    unsigned int r = (x.v + 0x7fffu + ((x.v >> 16) & 1u)) >> 16;   // RTNE
    return (unsigned short)r;
}

__global__ void k_zero(float* __restrict__ pool, float* __restrict__ cntf) {
    int i = threadIdx.x;
    if (i < N_GRAPHS) { pool[i] = 0.0f; cntf[i] = 0.0f; }
}

// W [KSRC][100] f32 -> Wt [112][128] bf16 (transposed, zero-padded)
__global__ void k_wt(const float* __restrict__ W, int KSRC, unsigned short* __restrict__ Wt) {
    int idx = blockIdx.x * 256 + threadIdx.x;
    if (idx >= 112 * 128) return;
    int c = idx >> 7, k = idx & 127;
    float v = (k < KSRC && c < HID) ? W[k * HID + c] : 0.0f;
    Wt[c * 128 + k] = f2b(v);
}

// ---- CSR build: two-level counting sort (round-6: k_fill had 16x write amp, 50us) ----
// p1: per-block histogram by bucket (dst>>8)
__global__ __launch_bounds__(256) void k_p1(const int* __restrict__ dst, int E,
                                            int* __restrict__ bbins) {
    __shared__ int hist[256];
    const int t = threadIdx.x, b = blockIdx.x;
    hist[t] = 0;
    __syncthreads();
    int e0 = b * BKE, e1 = min(e0 + BKE, E);
    for (int e = e0 + t; e < e1; e += 256) atomicAdd(&hist[dst[e] >> 8], 1);
    __syncthreads();
    if (t < NBIN) bbins[b * NBIN + t] = hist[t];
}

// p2: bucket bases + per-(block,bucket) offsets; also rowptr[N]=E
__global__ __launch_bounds__(256) void k_p2(const int* __restrict__ bbins, int nb, int E,
                                            int* __restrict__ boff, int* __restrict__ bbase,
                                            int* __restrict__ rowptr) {
    __shared__ int tot[256], sb[256];
    const int t = threadIdx.x;
    int s = 0;
    if (t < NBIN)
        for (int b = 0; b < nb; ++b) s += bbins[b * NBIN + t];
    tot[t] = (t < NBIN) ? s : 0;
    __syncthreads();
    sb[t] = tot[t];
    __syncthreads();
    for (int off = 1; off < 256; off <<= 1) {
        int v = (t >= off) ? sb[t - off] : 0;
        __syncthreads();
        sb[t] += v;
        __syncthreads();
    }
    int base = sb[t] - tot[t];   // exclusive
    if (t < NBIN) {
        bbase[t] = base;
        int run = base;
        for (int b = 0; b < nb; ++b) { boff[b * NBIN + t] = run; run += bbins[b * NBIN + t]; }
    }
    if (t == 0) { bbase[NBIN] = E; rowptr[N_NODES] = E; }
}

// p3: local counting sort by bucket, write packed edges in contiguous per-bin runs
__global__ __launch_bounds__(256) void k_p3(const int* __restrict__ src, const int* __restrict__ dst,
                                            int E, const int* __restrict__ boff,
                                            unsigned int* __restrict__ bE) {
    __shared__ unsigned int stage[BKE];
    __shared__ int hist[256], pref[256], cur[256], sb[256], offr[NBIN];
    const int t = threadIdx.x, b = blockIdx.x;
    hist[t] = 0;
    if (t < NBIN) offr[t] = boff[b * NBIN + t];
    __syncthreads();
    int e0 = b * BKE, e1 = min(e0 + BKE, E), n = e1 - e0;
    unsigned int mine[BKE / 256];
    int cnt = 0;
    for (int e = e0 + t; e < e1; e += 256) {
        unsigned int v = ((unsigned int)src[e] << 16) | (unsigned int)dst[e];
        mine[cnt++] = v;
        atomicAdd(&hist[(v >> 8) & 255], 1);
    }
    __syncthreads();
    sb[t] = hist[t];
    __syncthreads();
    for (int off = 1; off < 256; off <<= 1) {
        int v = (t >= off) ? sb[t - off] : 0;
        __syncthreads();
        sb[t] += v;
        __syncthreads();
    }
    pref[t] = sb[t] - hist[t];
    cur[t] = pref[t];
    __syncthreads();
    for (int c = 0; c < cnt; ++c) {
        unsigned int v = mine[c];
        int p = atomicAdd(&cur[(v >> 8) & 255], 1);
        stage[p] = v;
    }
    __syncthreads();
    for (int i = t; i < n; i += 256) {
        unsigned int v = stage[i];
        int bin = (v >> 8) & 255;
        bE[offr[bin] + (i - pref[bin])] = v;
    }
}

// p4: per-bucket sort by node -> rowptr, dinv, eidx (scatter confined to 16KB region)
__global__ __launch_bounds__(256) void k_p4(const unsigned int* __restrict__ bE,
                                            const int* __restrict__ bbase,
                                            int* __restrict__ rowptr, int* __restrict__ eidx,
                                            float* __restrict__ dinv) {
    __shared__ int hist[256], pref[256], cur[256], sb[256];
    const int t = threadIdx.x, b = blockIdx.x;
    const int eBase = bbase[b], eEnd = bbase[b + 1], n = eEnd - eBase;
    hist[t] = 0;
    __syncthreads();
    for (int i = t; i < n; i += 256) atomicAdd(&hist[bE[eBase + i] & 255], 1);
    __syncthreads();
    sb[t] = hist[t];
    __syncthreads();
    for (int off = 1; off < 256; off <<= 1) {
        int v = (t >= off) ? sb[t - off] : 0;
        __syncthreads();
        sb[t] += v;
        __syncthreads();
    }
    pref[t] = sb[t] - hist[t];
    cur[t] = pref[t];
    int node = (b << 8) + t;
    if (node < N_NODES) {
        rowptr[node] = eBase + pref[t];
        dinv[node] = rsqrtf((float)(hist[t] + 1));   // +1 self loop
    }
    __syncthreads();
    for (int i = t; i < n; i += 256) {
        unsigned int v = bE[eBase + i];
        int p = atomicAdd(&cur[v & 255], 1);
        eidx[eBase + p] = (int)(v >> 16);
    }
}

// MFMA bf16 GEMM: out[i][c] = f2b(dinv[i] * sum_k A[i][k] * W[k][c]), out [N][HP] bf16.
template<bool ABF16>
__global__ __launch_bounds__(256) void k_gemm(const void* __restrict__ Asrc,
                                              const unsigned short* __restrict__ Wt, // [112][128]
                                              const float* __restrict__ dinv,
                                              unsigned short* __restrict__ out) {
    __shared__ __align__(16) unsigned short xs[64][136];
    __shared__ __align__(16) unsigned short ws[112][136];
    const int t = threadIdx.x;
    const int base = blockIdx.x * 64;

    for (int idx = t; idx < 112 * 64; idx += 256) {
        int c = idx >> 6, u = idx & 63;
        *(unsigned int*)&ws[c][2 * u] = ((const unsigned int*)Wt)[idx];
    }
    if (ABF16) {
        const unsigned short* A = (const unsigned short*)Asrc;   // [N][HP] bf16
        for (int idx = t; idx < 64 * 16; idx += 256) {
            int r = idx >> 4, q = idx & 15;
            int row = base + r;
            uint4 v = make_uint4(0, 0, 0, 0);
            if (q < 13 && row < N_NODES)
                v = ((const uint4*)(A + (size_t)row * HP))[q];
            *(uint4*)&xs[r][8 * q] = v;
        }
    } else {
        const float* A = (const float*)Asrc;                     // [N][128] f32
        for (int idx = t; idx < 64 * 32; idx += 256) {
            int r = idx >> 5, q = idx & 31;
            int row = base + r;
            ushort4 p;
            if (row < N_NODES) {
                float4 v = ((const float4*)(A + (size_t)row * 128))[q];
                p.x = f2b(v.x); p.y = f2b(v.y); p.z = f2b(v.z); p.w = f2b(v.w);
            } else p = make_ushort4(0, 0, 0, 0);
            *(ushort4*)&xs[r][4 * q] = p;
        }
    }
    __syncthreads();

    const int lane = t & 63, w = t >> 6;
    const int g = lane >> 4, cl = lane & 15;

    floatx4 acc[7];
#pragma unroll
    for (int n = 0; n < 7; ++n) acc[n] = (floatx4){0.f, 0.f, 0.f, 0.f};

#pragma unroll
    for (int kc = 0; kc < 4; ++kc) {
        short8 a = *(const short8*)&xs[w * 16 + cl][kc * 32 + 8 * g];
#pragma unroll
        for (int n = 0; n < 7; ++n) {
            short8 b = *(const short8*)&ws[n * 16 + cl][kc * 32 + 8 * g];
            acc[n] = __builtin_amdgcn_mfma_f32_16x16x32_bf16(a, b, acc[n], 0, 0, 0);
        }
    }

    float di[4]; int grows[4];
#pragma unroll
    for (int r = 0; r < 4; ++r) {
        grows[r] = base + w * 16 + 4 * g + r;
        di[r] = (grows[r] < N_NODES) ? dinv[grows[r]] : 0.0f;
    }
#pragma unroll
    for (int n = 0; n < 7; ++n) {
        int gcol = n * 16 + cl;
        if (gcol >= HP) continue;
#pragma unroll
        for (int r = 0; r < 4; ++r) {
            if (grows[r] < N_NODES)
                out[(size_t)grows[r] * HP + gcol] = f2b(acc[n][r] * di[r]);
        }
    }
}

// layer-1 aggregate+finish: h1 = tanh(dinv*(hs_self + sum hs[src]) + b1), bf16 in/out.
__global__ void k_gather1(const int* __restrict__ rowptr, const int* __restrict__ eidx,
                          const unsigned short* __restrict__ hs, const float* __restrict__ dinv,
                          const float* __restrict__ b1, unsigned short* __restrict__ h1) {
    int w = blockIdx.x * blockDim.x + threadIdx.x;
    if (w >= N_NODES * 13) return;
    int i = w / 13, c = w % 13;
    const int c0 = 8 * c;
    float s[8];
    uint4 sv = *(const uint4*)(hs + (size_t)i * HP + c0);
    s[0] = b2f(sv.x & 0xffff); s[1] = b2f(sv.x >> 16);
    s[2] = b2f(sv.y & 0xffff); s[3] = b2f(sv.y >> 16);
    s[4] = b2f(sv.z & 0xffff); s[5] = b2f(sv.z >> 16);
    s[6] = b2f(sv.w & 0xffff); s[7] = b2f(sv.w >> 16);
    int beg = rowptr[i], end = rowptr[i + 1];
    for (int e = beg; e < end; ++e) {
        int sn = eidx[e];
        uint4 v = *(const uint4*)(hs + (size_t)sn * HP + c0);
        s[0] += b2f(v.x & 0xffff); s[1] += b2f(v.x >> 16);
        s[2] += b2f(v.y & 0xffff); s[3] += b2f(v.y >> 16);
        s[4] += b2f(v.z & 0xffff); s[5] += b2f(v.z >> 16);
        s[6] += b2f(v.w & 0xffff); s[7] += b2f(v.w >> 16);
    }
    float di = dinv[i];
    unsigned short o[8];
    if (c < 12) {
#pragma unroll
        for (int j = 0; j < 8; ++j) o[j] = f2b(tanhf(di * s[j] + b1[c0 + j]));
    } else {
#pragma unroll
        for (int j = 0; j < 4; ++j) o[j] = f2b(tanhf(di * s[j] + b1[96 + j]));
#pragma unroll
        for (int j = 4; j < 8; ++j) o[j] = 0;   // pad cols must stay 0
    }
    uint4 ov;
    ov.x = (unsigned int)o[0] | ((unsigned int)o[1] << 16);
    ov.y = (unsigned int)o[2] | ((unsigned int)o[3] << 16);
    ov.z = (unsigned int)o[4] | ((unsigned int)o[5] << 16);
    ov.w = (unsigned int)o[6] | ((unsigned int)o[7] << 16);
    *(uint4*)(h1 + (size_t)i * HP + c0) = ov;
}

// layer-2 aggregate: acc = hs_self + sum hs[src]
__global__ void k_gather2(const int* __restrict__ rowptr, const int* __restrict__ eidx,
                          const unsigned short* __restrict__ hs, unsigned short* __restrict__ acc) {
    int w = blockIdx.x * blockDim.x + threadIdx.x;
    if (w >= N_NODES * 13) return;
    int i = w / 13, c = w % 13;
    const int c0 = 8 * c;
    float s[8];
    uint4 sv = *(const uint4*)(hs + (size_t)i * HP + c0);
    s[0] = b2f(sv.x & 0xffff); s[1] = b2f(sv.x >> 16);
    s[2] = b2f(sv.y & 0xffff); s[3] = b2f(sv.y >> 16);
    s[4] = b2f(sv.z & 0xffff); s[5] = b2f(sv.z >> 16);
    s[6] = b2f(sv.w & 0xffff); s[7] = b2f(sv.w >> 16);
    int beg = rowptr[i], end = rowptr[i + 1];
    for (int e = beg; e < end; ++e) {
        int sn = eidx[e];
        uint4 v = *(const uint4*)(hs + (size_t)sn * HP + c0);
        s[0] += b2f(v.x & 0xffff); s[1] += b2f(v.x >> 16);
        s[2] += b2f(v.y & 0xffff); s[3] += b2f(v.y >> 16);
        s[4] += b2f(v.z & 0xffff); s[5] += b2f(v.z >> 16);
        s[6] += b2f(v.w & 0xffff); s[7] += b2f(v.w >> 16);
    }
    uint4 ov;
    ov.x = (unsigned int)f2b(s[0]) | ((unsigned int)f2b(s[1]) << 16);
    ov.y = (unsigned int)f2b(s[2]) | ((unsigned int)f2b(s[3]) << 16);
    ov.z = (unsigned int)f2b(s[4]) | ((unsigned int)f2b(s[5]) << 16);
    ov.w = (unsigned int)f2b(s[6]) | ((unsigned int)f2b(s[7]) << 16);
    *(uint4*)(acc + (size_t)i * HP + c0) = ov;
}

// per node -> block-local LDS reduction by graph -> <=64 global atomics per block
__global__ __launch_bounds__(256) void k_pool(const float* __restrict__ dinv,
                                              const unsigned short* __restrict__ accb,
                                              const float* __restrict__ Wlin,
                                              const int* __restrict__ batch,
                                              float* __restrict__ pool,
                                              float* __restrict__ cnt) {
    __shared__ float sp[N_GRAPHS];
    __shared__ float sc[N_GRAPHS];
    const int t = threadIdx.x;
    if (t < N_GRAPHS) { sp[t] = 0.0f; sc[t] = 0.0f; }
    __syncthreads();
    int i = blockIdx.x * blockDim.x + t;
    if (i < N_NODES) {
        float di = dinv[i];
        float s = 0.0f;
#pragma unroll
        for (int jc = 0; jc < 25; ++jc) {
            uint2 v = *(const uint2*)(accb + (size_t)i * HP + 4 * jc);
            float4 wl = ((const float4*)Wlin)[jc];
            s += b2f(v.x & 0xffff) * wl.x + b2f(v.x >> 16) * wl.y
               + b2f(v.y & 0xffff) * wl.z + b2f(v.y >> 16) * wl.w;
        }
        s *= di;
        int g = batch[i];
        atomicAdd(&sp[g], s);
        atomicAdd(&sc[g], 1.0f);
    }
    __syncthreads();
    if (t < N_GRAPHS && sc[t] != 0.0f) {
        atomicAdd(&pool[t], sp[t]);
        atomicAdd(&cnt[t], sc[t]);
    }
}

__global__ void k_final(const float* __restrict__ pool, const float* __restrict__ cnt,
                        const float* __restrict__ b2, const float* __restrict__ Wlin,
                        const float* __restrict__ blin, float* __restrict__ out) {
    int g = threadIdx.x;
    if (g >= N_GRAPHS) return;
    float c2 = 0.0f;
    for (int j = 0; j < HID; ++j) c2 += b2[j] * Wlin[j];
    out[g] = pool[g] / fmaxf(cnt[g], 1.0f) + c2 + blin[0];
}

extern "C" void kernel_launch(void* const* d_in, const int* in_sizes, int n_in,
                              void* d_out, int out_size, void* d_ws, size_t ws_size,
                              hipStream_t stream) {
    const float* x    = (const float*)d_in[0];
    const int*   ei   = (const int*)d_in[1];
    const int*   batch= (const int*)d_in[2];
    const float* W1   = (const float*)d_in[3];
    const float* b1   = (const float*)d_in[4];
    const float* W2   = (const float*)d_in[5];
    const float* b2   = (const float*)d_in[6];
    const float* Wlin = (const float*)d_in[7];
    const float* blin = (const float*)d_in[8];
    float* out = (float*)d_out;

    const int E = in_sizes[1] / 2;
    const int* src = ei;
    const int* dst = ei + E;

    float* wsf  = (float*)d_ws;
    int*   wsi  = (int*)d_ws;
    float* dinv = wsf + OFF_DINV;
    float* cntf = wsf + OFF_CNTF;
    float* pool = wsf + OFF_POOL;
    unsigned short* Wt1 = (unsigned short*)(wsf + OFF_WT1);
    unsigned short* Wt2 = (unsigned short*)(wsf + OFF_WT2);
    unsigned short* HS  = (unsigned short*)(wsf + OFF_HS);
    unsigned short* H1  = (unsigned short*)(wsf + OFF_H1);
    unsigned short* ACC = (unsigned short*)(wsf + OFF_ACC);
    int* rowptr = wsi + OFF_ROWPTR;
    int* eidx   = wsi + OFF_EIDX;
    unsigned int* bE = (unsigned int*)(wsi + OFF_BE);
    int* bbins  = wsi + OFF_BBINS;
    int* boff   = wsi + OFF_BOFF;
    int* bbase  = wsi + OFF_BBASE;

    const int nbE = (E + BKE - 1) / BKE;   // 196 for E=800k (<= MAXBLK)

    // CSR build (two-level counting sort) + dinv + weight transposes
    k_zero<<<1, 128, 0, stream>>>(pool, cntf);
    k_wt<<<56, 256, 0, stream>>>(W1, 128, Wt1);
    k_wt<<<56, 256, 0, stream>>>(W2, 100, Wt2);
    k_p1<<<nbE, 256, 0, stream>>>(dst, E, bbins);
    k_p2<<<1, 256, 0, stream>>>(bbins, nbE, E, boff, bbase, rowptr);
    k_p3<<<nbE, 256, 0, stream>>>(src, dst, E, boff, bE);
    k_p4<<<NBIN, 256, 0, stream>>>(bE, bbase, rowptr, eidx, dinv);

    // layer 1
    k_gemm<false><<<(N_NODES + 63) / 64, 256, 0, stream>>>(x, Wt1, dinv, HS);
    k_gather1<<<(N_NODES * 13 + 255) / 256, 256, 0, stream>>>(rowptr, eidx, HS, dinv, b1, H1);

    // layer 2
    k_gemm<true><<<(N_NODES + 63) / 64, 256, 0, stream>>>(H1, Wt2, dinv, HS);
    k_gather2<<<(N_NODES * 13 + 255) / 256, 256, 0, stream>>>(rowptr, eidx, HS, ACC);

    // readout
    k_pool<<<(N_NODES + 255) / 256, 256, 0, stream>>>(dinv, ACC, Wlin, batch, pool, cntf);
    k_final<<<1, 64, 0, stream>>>(pool, cntf, b2, Wlin, blin, out);
}

// Round 8
// 182.169 us; speedup vs baseline: 54.8745x; 1.2241x over previous
//
#include <hip/hip_runtime.h>
#include <hip/hip_bf16.h>

#define N_NODES 50000
#define N_GRAPHS 64
#define HID 100
#define HP 104            // padded bf16 row stride (13 * 8)

#define BKE  4096         // edges per block in p1/p3
#define NBIN 196          // buckets of 256 nodes: ceil(50000/256)
#define MAXBLK 256        // max edge-blocks supported (E <= 1M)

// ---- workspace layout (float offsets) ----
#define OFF_DINV 0
#define OFF_CNTF 50048
#define OFF_POOL 50112
#define OFF_WT1  50176                    // bf16 [112][128] = 7168 floats
#define OFF_WT2  57344
#define OFF_HS   64512                    // bf16 [N][104] = 2.6M floats
#define OFF_H1   2664512                  // bf16 [N][104]
#define OFF_ACC  5264512                  // bf16 [N][104]
#define OFF_ROWPTR 7864512                // N+1 ints
#define OFF_EIDX   7914560                // E ints
#define OFF_BE     8714560                // E uints (packed (src<<16)|dst, bucketed)
#define OFF_BBINS  9514560                // [MAXBLK][NBIN] ints
#define OFF_BOFF   9565760                // [MAXBLK][NBIN] ints
#define OFF_BTOT   9616960                // NBIN ints
#define OFF_BBASE  9617216                // NBIN+1 ints
// end ~9,617,728 floats = 38.5 MB

typedef __attribute__((ext_vector_type(8))) short short8;
typedef __attribute__((ext_vector_type(4))) float floatx4;

__device__ inline float b2f(unsigned int u) {
    union { unsigned int v; float f; } x; x.v = u << 16; return x.f;
}
__device__ inline unsigned short f2b(float f) {
    union { float f; unsigned int v; } x; x.f = f;
    unsigned int r = (x.v + 0x7fffu + ((x.v >> 16) & 1u)) >> 16;   // RTNE
    return (unsigned short)r;
}

__global__ void k_zero(float* __restrict__ pool, float* __restrict__ cntf) {
    int i = threadIdx.x;
    if (i < N_GRAPHS) { pool[i] = 0.0f; cntf[i] = 0.0f; }
}

// W [KSRC][100] f32 -> Wt [112][128] bf16 (transposed, zero-padded)
__global__ void k_wt(const float* __restrict__ W, int KSRC, unsigned short* __restrict__ Wt) {
    int idx = blockIdx.x * 256 + threadIdx.x;
    if (idx >= 112 * 128) return;
    int c = idx >> 7, k = idx & 127;
    float v = (k < KSRC && c < HID) ? W[k * HID + c] : 0.0f;
    Wt[c * 128 + k] = f2b(v);
}

// ---- CSR build: two-level counting sort ----
// p1: per-block histogram by bucket (dst>>8)
__global__ __launch_bounds__(256) void k_p1(const int* __restrict__ dst, int E,
                                            int* __restrict__ bbins) {
    __shared__ int hist[256];
    const int t = threadIdx.x, b = blockIdx.x;
    hist[t] = 0;
    __syncthreads();
    int e0 = b * BKE, e1 = min(e0 + BKE, E);
    for (int e = e0 + t; e < e1; e += 256) atomicAdd(&hist[dst[e] >> 8], 1);
    __syncthreads();
    if (t < NBIN) bbins[b * NBIN + t] = hist[t];
}

// p2a: per-bucket scan over edge-blocks (round-7: serial single-block p2 was 48us
// at 0.04% occupancy). Block j: boff[b][j] = sum_{b'<b} bbins[b'][j]; tot[j] = total.
__global__ __launch_bounds__(256) void k_p2a(const int* __restrict__ bbins, int nb,
                                             int* __restrict__ boff, int* __restrict__ btot) {
    __shared__ int sb[256];
    const int t = threadIdx.x, j = blockIdx.x;
    int v = (t < nb) ? bbins[t * NBIN + j] : 0;
    sb[t] = v;
    __syncthreads();
    for (int off = 1; off < 256; off <<= 1) {
        int u = (t >= off) ? sb[t - off] : 0;
        __syncthreads();
        sb[t] += u;
        __syncthreads();
    }
    if (t < nb) boff[t * NBIN + j] = sb[t] - v;   // exclusive, bucket-local
    if (t == 255) btot[j] = sb[255];
}

// p2b: exclusive scan of bucket totals -> bbase; tails.
__global__ __launch_bounds__(256) void k_p2b(const int* __restrict__ btot, int E,
                                             int* __restrict__ bbase, int* __restrict__ rowptr) {
    __shared__ int sb[256];
    const int t = threadIdx.x;
    int v = (t < NBIN) ? btot[t] : 0;
    sb[t] = v;
    __syncthreads();
    for (int off = 1; off < 256; off <<= 1) {
        int u = (t >= off) ? sb[t - off] : 0;
        __syncthreads();
        sb[t] += u;
        __syncthreads();
    }
    if (t < NBIN) bbase[t] = sb[t] - v;
    if (t == 0) { bbase[NBIN] = E; rowptr[N_NODES] = E; }
}

// p3: local counting sort by bucket, write packed edges in contiguous per-bin runs
__global__ __launch_bounds__(256) void k_p3(const int* __restrict__ src, const int* __restrict__ dst,
                                            int E, const int* __restrict__ boff,
                                            const int* __restrict__ bbase,
                                            unsigned int* __restrict__ bE) {
    __shared__ unsigned int stage[BKE];
    __shared__ int hist[256], pref[256], cur[256], sb[256], offr[NBIN];
    const int t = threadIdx.x, b = blockIdx.x;
    hist[t] = 0;
    if (t < NBIN) offr[t] = boff[b * NBIN + t] + bbase[t];
    __syncthreads();
    int e0 = b * BKE, e1 = min(e0 + BKE, E), n = e1 - e0;
    unsigned int mine[BKE / 256];
    int cnt = 0;
    for (int e = e0 + t; e < e1; e += 256) {
        unsigned int v = ((unsigned int)src[e] << 16) | (unsigned int)dst[e];
        mine[cnt++] = v;
        atomicAdd(&hist[(v >> 8) & 255], 1);
    }
    __syncthreads();
    sb[t] = hist[t];
    __syncthreads();
    for (int off = 1; off < 256; off <<= 1) {
        int v = (t >= off) ? sb[t - off] : 0;
        __syncthreads();
        sb[t] += v;
        __syncthreads();
    }
    pref[t] = sb[t] - hist[t];
    cur[t] = pref[t];
    __syncthreads();
    for (int c = 0; c < cnt; ++c) {
        unsigned int v = mine[c];
        int p = atomicAdd(&cur[(v >> 8) & 255], 1);
        stage[p] = v;
    }
    __syncthreads();
    for (int i = t; i < n; i += 256) {
        unsigned int v = stage[i];
        int bin = (v >> 8) & 255;
        bE[offr[bin] + (i - pref[bin])] = v;
    }
}

// p4: per-bucket sort by node -> rowptr, dinv, eidx (scatter confined to 16KB region)
__global__ __launch_bounds__(256) void k_p4(const unsigned int* __restrict__ bE,
                                            const int* __restrict__ bbase,
                                            int* __restrict__ rowptr, int* __restrict__ eidx,
                                            float* __restrict__ dinv) {
    __shared__ int hist[256], pref[256], cur[256], sb[256];
    const int t = threadIdx.x, b = blockIdx.x;
    const int eBase = bbase[b], eEnd = bbase[b + 1], n = eEnd - eBase;
    hist[t] = 0;
    __syncthreads();
    for (int i = t; i < n; i += 256) atomicAdd(&hist[bE[eBase + i] & 255], 1);
    __syncthreads();
    sb[t] = hist[t];
    __syncthreads();
    for (int off = 1; off < 256; off <<= 1) {
        int v = (t >= off) ? sb[t - off] : 0;
        __syncthreads();
        sb[t] += v;
        __syncthreads();
    }
    pref[t] = sb[t] - hist[t];
    cur[t] = pref[t];
    int node = (b << 8) + t;
    if (node < N_NODES) {
        rowptr[node] = eBase + pref[t];
        dinv[node] = rsqrtf((float)(hist[t] + 1));   // +1 self loop
    }
    __syncthreads();
    for (int i = t; i < n; i += 256) {
        unsigned int v = bE[eBase + i];
        int p = atomicAdd(&cur[v & 255], 1);
        eidx[eBase + p] = (int)(v >> 16);
    }
}

// MFMA bf16 GEMM: out[i][c] = f2b(dinv[i] * sum_k A[i][k] * W[k][c]), out [N][HP] bf16.
template<bool ABF16>
__global__ __launch_bounds__(256) void k_gemm(const void* __restrict__ Asrc,
                                              const unsigned short* __restrict__ Wt, // [112][128]
                                              const float* __restrict__ dinv,
                                              unsigned short* __restrict__ out) {
    __shared__ __align__(16) unsigned short xs[64][136];
    __shared__ __align__(16) unsigned short ws[112][136];
    const int t = threadIdx.x;
    const int base = blockIdx.x * 64;

    for (int idx = t; idx < 112 * 64; idx += 256) {
        int c = idx >> 6, u = idx & 63;
        *(unsigned int*)&ws[c][2 * u] = ((const unsigned int*)Wt)[idx];
    }
    if (ABF16) {
        const unsigned short* A = (const unsigned short*)Asrc;   // [N][HP] bf16
        for (int idx = t; idx < 64 * 16; idx += 256) {
            int r = idx >> 4, q = idx & 15;
            int row = base + r;
            uint4 v = make_uint4(0, 0, 0, 0);
            if (q < 13 && row < N_NODES)
                v = ((const uint4*)(A + (size_t)row * HP))[q];
            *(uint4*)&xs[r][8 * q] = v;
        }
    } else {
        const float* A = (const float*)Asrc;                     // [N][128] f32
        for (int idx = t; idx < 64 * 32; idx += 256) {
            int r = idx >> 5, q = idx & 31;
            int row = base + r;
            ushort4 p;
            if (row < N_NODES) {
                float4 v = ((const float4*)(A + (size_t)row * 128))[q];
                p.x = f2b(v.x); p.y = f2b(v.y); p.z = f2b(v.z); p.w = f2b(v.w);
            } else p = make_ushort4(0, 0, 0, 0);
            *(ushort4*)&xs[r][4 * q] = p;
        }
    }
    __syncthreads();

    const int lane = t & 63, w = t >> 6;
    const int g = lane >> 4, cl = lane & 15;

    floatx4 acc[7];
#pragma unroll
    for (int n = 0; n < 7; ++n) acc[n] = (floatx4){0.f, 0.f, 0.f, 0.f};

#pragma unroll
    for (int kc = 0; kc < 4; ++kc) {
        short8 a = *(const short8*)&xs[w * 16 + cl][kc * 32 + 8 * g];
#pragma unroll
        for (int n = 0; n < 7; ++n) {
            short8 b = *(const short8*)&ws[n * 16 + cl][kc * 32 + 8 * g];
            acc[n] = __builtin_amdgcn_mfma_f32_16x16x32_bf16(a, b, acc[n], 0, 0, 0);
        }
    }

    float di[4]; int grows[4];
#pragma unroll
    for (int r = 0; r < 4; ++r) {
        grows[r] = base + w * 16 + 4 * g + r;
        di[r] = (grows[r] < N_NODES) ? dinv[grows[r]] : 0.0f;
    }
#pragma unroll
    for (int n = 0; n < 7; ++n) {
        int gcol = n * 16 + cl;
        if (gcol >= HP) continue;
#pragma unroll
        for (int r = 0; r < 4; ++r) {
            if (grows[r] < N_NODES)
                out[(size_t)grows[r] * HP + gcol] = f2b(acc[n][r] * di[r]);
        }
    }
}

// layer-1 aggregate+finish: h1 = tanh(dinv*(hs_self + sum hs[src]) + b1), bf16 in/out.
__global__ void k_gather1(const int* __restrict__ rowptr, const int* __restrict__ eidx,
                          const unsigned short* __restrict__ hs, const float* __restrict__ dinv,
                          const float* __restrict__ b1, unsigned short* __restrict__ h1) {
    int w = blockIdx.x * blockDim.x + threadIdx.x;
    if (w >= N_NODES * 13) return;
    int i = w / 13, c = w % 13;
    const int c0 = 8 * c;
    float s[8];
    uint4 sv = *(const uint4*)(hs + (size_t)i * HP + c0);
    s[0] = b2f(sv.x & 0xffff); s[1] = b2f(sv.x >> 16);
    s[2] = b2f(sv.y & 0xffff); s[3] = b2f(sv.y >> 16);
    s[4] = b2f(sv.z & 0xffff); s[5] = b2f(sv.z >> 16);
    s[6] = b2f(sv.w & 0xffff); s[7] = b2f(sv.w >> 16);
    int beg = rowptr[i], end = rowptr[i + 1];
    for (int e = beg; e < end; ++e) {
        int sn = eidx[e];
        uint4 v = *(const uint4*)(hs + (size_t)sn * HP + c0);
        s[0] += b2f(v.x & 0xffff); s[1] += b2f(v.x >> 16);
        s[2] += b2f(v.y & 0xffff); s[3] += b2f(v.y >> 16);
        s[4] += b2f(v.z & 0xffff); s[5] += b2f(v.z >> 16);
        s[6] += b2f(v.w & 0xffff); s[7] += b2f(v.w >> 16);
    }
    float di = dinv[i];
    unsigned short o[8];
    if (c < 12) {
#pragma unroll
        for (int j = 0; j < 8; ++j) o[j] = f2b(tanhf(di * s[j] + b1[c0 + j]));
    } else {
#pragma unroll
        for (int j = 0; j < 4; ++j) o[j] = f2b(tanhf(di * s[j] + b1[96 + j]));
#pragma unroll
        for (int j = 4; j < 8; ++j) o[j] = 0;   // pad cols must stay 0
    }
    uint4 ov;
    ov.x = (unsigned int)o[0] | ((unsigned int)o[1] << 16);
    ov.y = (unsigned int)o[2] | ((unsigned int)o[3] << 16);
    ov.z = (unsigned int)o[4] | ((unsigned int)o[5] << 16);
    ov.w = (unsigned int)o[6] | ((unsigned int)o[7] << 16);
    *(uint4*)(h1 + (size_t)i * HP + c0) = ov;
}

// layer-2 aggregate: acc = hs_self + sum hs[src]
__global__ void k_gather2(const int* __restrict__ rowptr, const int* __restrict__ eidx,
                          const unsigned short* __restrict__ hs, unsigned short* __restrict__ acc) {
    int w = blockIdx.x * blockDim.x + threadIdx.x;
    if (w >= N_NODES * 13) return;
    int i = w / 13, c = w % 13;
    const int c0 = 8 * c;
    float s[8];
    uint4 sv = *(const uint4*)(hs + (size_t)i * HP + c0);
    s[0] = b2f(sv.x & 0xffff); s[1] = b2f(sv.x >> 16);
    s[2] = b2f(sv.y & 0xffff); s[3] = b2f(sv.y >> 16);
    s[4] = b2f(sv.z & 0xffff); s[5] = b2f(sv.z >> 16);
    s[6] = b2f(sv.w & 0xffff); s[7] = b2f(sv.w >> 16);
    int beg = rowptr[i], end = rowptr[i + 1];
    for (int e = beg; e < end; ++e) {
        int sn = eidx[e];
        uint4 v = *(const uint4*)(hs + (size_t)sn * HP + c0);
        s[0] += b2f(v.x & 0xffff); s[1] += b2f(v.x >> 16);
        s[2] += b2f(v.y & 0xffff); s[3] += b2f(v.y >> 16);
        s[4] += b2f(v.z & 0xffff); s[5] += b2f(v.z >> 16);
        s[6] += b2f(v.w & 0xffff); s[7] += b2f(v.w >> 16);
    }
    uint4 ov;
    ov.x = (unsigned int)f2b(s[0]) | ((unsigned int)f2b(s[1]) << 16);
    ov.y = (unsigned int)f2b(s[2]) | ((unsigned int)f2b(s[3]) << 16);
    ov.z = (unsigned int)f2b(s[4]) | ((unsigned int)f2b(s[5]) << 16);
    ov.w = (unsigned int)f2b(s[6]) | ((unsigned int)f2b(s[7]) << 16);
    *(uint4*)(acc + (size_t)i * HP + c0) = ov;
}

// per node -> block-local LDS reduction by graph -> <=64 global atomics per block
__global__ __launch_bounds__(256) void k_pool(const float* __restrict__ dinv,
                                              const unsigned short* __restrict__ accb,
                                              const float* __restrict__ Wlin,
                                              const int* __restrict__ batch,
                                              float* __restrict__ pool,
                                              float* __restrict__ cnt) {
    __shared__ float sp[N_GRAPHS];
    __shared__ float sc[N_GRAPHS];
    const int t = threadIdx.x;
    if (t < N_GRAPHS) { sp[t] = 0.0f; sc[t] = 0.0f; }
    __syncthreads();
    int i = blockIdx.x * blockDim.x + t;
    if (i < N_NODES) {
        float di = dinv[i];
        float s = 0.0f;
#pragma unroll
        for (int jc = 0; jc < 25; ++jc) {
            uint2 v = *(const uint2*)(accb + (size_t)i * HP + 4 * jc);
            float4 wl = ((const float4*)Wlin)[jc];
            s += b2f(v.x & 0xffff) * wl.x + b2f(v.x >> 16) * wl.y
               + b2f(v.y & 0xffff) * wl.z + b2f(v.y >> 16) * wl.w;
        }
        s *= di;
        int g = batch[i];
        atomicAdd(&sp[g], s);
        atomicAdd(&sc[g], 1.0f);
    }
    __syncthreads();
    if (t < N_GRAPHS && sc[t] != 0.0f) {
        atomicAdd(&pool[t], sp[t]);
        atomicAdd(&cnt[t], sc[t]);
    }
}

__global__ void k_final(const float* __restrict__ pool, const float* __restrict__ cnt,
                        const float* __restrict__ b2, const float* __restrict__ Wlin,
                        const float* __restrict__ blin, float* __restrict__ out) {
    int g = threadIdx.x;
    if (g >= N_GRAPHS) return;
    float c2 = 0.0f;
    for (int j = 0; j < HID; ++j) c2 += b2[j] * Wlin[j];
    out[g] = pool[g] / fmaxf(cnt[g], 1.0f) + c2 + blin[0];
}

extern "C" void kernel_launch(void* const* d_in, const int* in_sizes, int n_in,
                              void* d_out, int out_size, void* d_ws, size_t ws_size,
                              hipStream_t stream) {
    const float* x    = (const float*)d_in[0];
    const int*   ei   = (const int*)d_in[1];
    const int*   batch= (const int*)d_in[2];
    const float* W1   = (const float*)d_in[3];
    const float* b1   = (const float*)d_in[4];
    const float* W2   = (const float*)d_in[5];
    const float* b2   = (const float*)d_in[6];
    const float* Wlin = (const float*)d_in[7];
    const float* blin = (const float*)d_in[8];
    float* out = (float*)d_out;

    const int E = in_sizes[1] / 2;
    const int* src = ei;
    const int* dst = ei + E;

    float* wsf  = (float*)d_ws;
    int*   wsi  = (int*)d_ws;
    float* dinv = wsf + OFF_DINV;
    float* cntf = wsf + OFF_CNTF;
    float* pool = wsf + OFF_POOL;
    unsigned short* Wt1 = (unsigned short*)(wsf + OFF_WT1);
    unsigned short* Wt2 = (unsigned short*)(wsf + OFF_WT2);
    unsigned short* HS  = (unsigned short*)(wsf + OFF_HS);
    unsigned short* H1  = (unsigned short*)(wsf + OFF_H1);
    unsigned short* ACC = (unsigned short*)(wsf + OFF_ACC);
    int* rowptr = wsi + OFF_ROWPTR;
    int* eidx   = wsi + OFF_EIDX;
    unsigned int* bE = (unsigned int*)(wsi + OFF_BE);
    int* bbins  = wsi + OFF_BBINS;
    int* boff   = wsi + OFF_BOFF;
    int* btot   = wsi + OFF_BTOT;
    int* bbase  = wsi + OFF_BBASE;

    const int nbE = (E + BKE - 1) / BKE;   // 196 for E=800k (<= MAXBLK)

    // CSR build (two-level counting sort) + dinv + weight transposes
    k_zero<<<1, 128, 0, stream>>>(pool, cntf);
    k_wt<<<56, 256, 0, stream>>>(W1, 128, Wt1);
    k_wt<<<56, 256, 0, stream>>>(W2, 100, Wt2);
    k_p1<<<nbE, 256, 0, stream>>>(dst, E, bbins);
    k_p2a<<<NBIN, 256, 0, stream>>>(bbins, nbE, boff, btot);
    k_p2b<<<1, 256, 0, stream>>>(btot, E, bbase, rowptr);
    k_p3<<<nbE, 256, 0, stream>>>(src, dst, E, boff, bbase, bE);
    k_p4<<<NBIN, 256, 0, stream>>>(bE, bbase, rowptr, eidx, dinv);

    // layer 1
    k_gemm<false><<<(N_NODES + 63) / 64, 256, 0, stream>>>(x, Wt1, dinv, HS);
    k_gather1<<<(N_NODES * 13 + 255) / 256, 256, 0, stream>>>(rowptr, eidx, HS, dinv, b1, H1);

    // layer 2
    k_gemm<true><<<(N_NODES + 63) / 64, 256, 0, stream>>>(H1, Wt2, dinv, HS);
    k_gather2<<<(N_NODES * 13 + 255) / 256, 256, 0, stream>>>(rowptr, eidx, HS, ACC);

    // readout
    k_pool<<<(N_NODES + 255) / 256, 256, 0, stream>>>(dinv, ACC, Wlin, batch, pool, cntf);
    k_final<<<1, 64, 0, stream>>>(pool, cntf, b2, Wlin, blin, out);
}